// Round 1
// baseline (2030.454 us; speedup 1.0000x reference)
//
#include <hip/hip_runtime.h>
#include <hip/hip_bf16.h>
#include <math.h>

#define S_TOT 262144   // 64^3
#define EPS_F 1e-5f

// ---------------------------------------------------------------------------
// Direct 3x3x3 conv, SAME padding. Input (B,CIN,64,64,64), weights (32,CIN,27),
// output (B,32,64,64,64). Optionally applies instance-norm + ReLU to the INPUT
// on load (fusing the previous layer's normalization).
// Block: 256 threads, one 8x8x8 spatial tile, all 32 couts.
// Thread: 8 voxels (one x-row) x 8 couts.
// ---------------------------------------------------------------------------
template<int CIN, bool NORM_IN>
__global__ __launch_bounds__(256)
void conv3d_k(const float* __restrict__ x, const float* __restrict__ w,
              const float* __restrict__ bias, const float* __restrict__ stats,
              float* __restrict__ y)
{
    constexpr int CHUNK = (CIN == 1) ? 1 : 4;
    __shared__ float sx[CHUNK][10][10][12];   // halo tile, x-padded to 12
    __shared__ float sw[32][CHUNK][27];

    const int blk = blockIdx.x;
    const int b   = blk >> 9;            // 512 tiles per batch
    const int t   = blk & 511;
    const int z0  = (t >> 6) << 3;
    const int y0  = ((t >> 3) & 7) << 3;
    const int x0  = (t & 7) << 3;
    const int tid = threadIdx.x;
    const int cg  = tid >> 6;            // cout group (0..3), = wave id
    const int vz  = (tid >> 3) & 7;
    const int vy  = tid & 7;

    float acc[8][8];
    #pragma unroll
    for (int q = 0; q < 8; ++q) {
        float bv = bias[cg*8 + q];
        #pragma unroll
        for (int xx = 0; xx < 8; ++xx) acc[q][xx] = bv;
    }

    for (int c0 = 0; c0 < CIN; c0 += CHUNK) {
        __syncthreads();
        // stage input tile (with halo) for this cin chunk
        for (int idx = tid; idx < CHUNK*1000; idx += 256) {
            int c   = idx / 1000;
            int rr  = idx - c*1000;
            int zz  = rr / 100;
            int rr2 = rr - zz*100;
            int yy  = rr2 / 10;
            int xx  = rr2 - yy*10;
            int gz = z0 + zz - 1, gy = y0 + yy - 1, gx = x0 + xx - 1;
            float v = 0.f;
            if ((unsigned)gz < 64u && (unsigned)gy < 64u && (unsigned)gx < 64u) {
                int bc = b*CIN + c0 + c;
                v = x[((size_t)bc << 18) + (gz << 12) + (gy << 6) + gx];
                if (NORM_IN) {
                    float m = stats[2*bc], rs = stats[2*bc + 1];
                    v = fmaxf(0.f, (v - m) * rs);
                }
            }
            sx[c][zz][yy][xx] = v;
        }
        // stage weights for this cin chunk
        for (int idx = tid; idx < 32*CHUNK*27; idx += 256) {
            int cout = idx / (CHUNK*27);
            int rr   = idx - cout*(CHUNK*27);
            int c    = rr / 27;
            int tap  = rr - c*27;
            sw[cout][c][tap] = w[(cout*CIN + c0 + c)*27 + tap];
        }
        __syncthreads();

        for (int c = 0; c < CHUNK; ++c) {
            #pragma unroll
            for (int dz = 0; dz < 3; ++dz) {
                #pragma unroll
                for (int dy = 0; dy < 3; ++dy) {
                    float row[10];
                    #pragma unroll
                    for (int k = 0; k < 10; ++k) row[k] = sx[c][vz+dz][vy+dy][k];
                    #pragma unroll
                    for (int q = 0; q < 8; ++q) {
                        #pragma unroll
                        for (int dx = 0; dx < 3; ++dx) {
                            float wv = sw[cg*8 + q][c][dz*9 + dy*3 + dx];
                            #pragma unroll
                            for (int xx = 0; xx < 8; ++xx)
                                acc[q][xx] = fmaf(row[xx+dx], wv, acc[q][xx]);
                        }
                    }
                }
            }
        }
    }

    #pragma unroll
    for (int q = 0; q < 8; ++q) {
        int cout = cg*8 + q;
        size_t base = ((size_t)(b*32 + cout) << 18) + ((size_t)(z0+vz) << 12)
                    + ((y0+vy) << 6) + x0;
        float4* p = (float4*)(y + base);
        p[0] = make_float4(acc[q][0], acc[q][1], acc[q][2], acc[q][3]);
        p[1] = make_float4(acc[q][4], acc[q][5], acc[q][6], acc[q][7]);
    }
}

// ---------------------------------------------------------------------------
// Instance-norm statistics: per (b,c) sum / sumsq partials (4 parts per plane)
// ---------------------------------------------------------------------------
__global__ __launch_bounds__(256)
void stats_partial_k(const float* __restrict__ y, float* __restrict__ raw)
{
    const int bc   = blockIdx.x >> 2;
    const int part = blockIdx.x & 3;
    const float4* p = (const float4*)(y + ((size_t)bc << 18) + part*65536);
    float s = 0.f, ss = 0.f;
    for (int i = threadIdx.x; i < 16384; i += 256) {
        float4 v = p[i];
        s  += v.x + v.y + v.z + v.w;
        ss += v.x*v.x + v.y*v.y + v.z*v.z + v.w*v.w;
    }
    #pragma unroll
    for (int off = 32; off > 0; off >>= 1) {
        s  += __shfl_down(s, off);
        ss += __shfl_down(ss, off);
    }
    __shared__ float sb[8];
    int wid = threadIdx.x >> 6, lane = threadIdx.x & 63;
    if (lane == 0) { sb[wid*2] = s; sb[wid*2 + 1] = ss; }
    __syncthreads();
    if (threadIdx.x == 0) {
        float ts = 0.f, tss = 0.f;
        for (int i = 0; i < 4; ++i) { ts += sb[i*2]; tss += sb[i*2 + 1]; }
        raw[(part*64 + bc)*2]     = ts;
        raw[(part*64 + bc)*2 + 1] = tss;
    }
}

__global__ void stats_final_k(const float* __restrict__ raw, float* __restrict__ stats)
{
    int bc = threadIdx.x;   // 64 threads
    float s = 0.f, ss = 0.f;
    for (int p = 0; p < 4; ++p) {
        s  += raw[(p*64 + bc)*2];
        ss += raw[(p*64 + bc)*2 + 1];
    }
    float mean = s * (1.f/262144.f);
    float var  = ss * (1.f/262144.f) - mean*mean;
    stats[2*bc]     = mean;
    stats[2*bc + 1] = rsqrtf(var + EPS_F);
}

// ---------------------------------------------------------------------------
// ROI pooling: roi_acc[b][r][c] += sum_s relu(norm(emb[b][c][s])) * mask[r][s]
// also accumulates cnt[r] = sum_s mask[r][s].
// Block: 256 threads = 64 (b,c) x 4 s-subgroups; 8 chunks of 128 s per block.
// ---------------------------------------------------------------------------
__global__ __launch_bounds__(256)
void roi_pool_k(const float* __restrict__ emb, const float* __restrict__ stats,
                const float* __restrict__ mask, float* __restrict__ roi_acc,
                float* __restrict__ cnt)
{
    __shared__ float se[64*132];     // [bc][g][k] : bc*132 + g*33 + k (swizzle pad)
    __shared__ float sacc[90*66];    // [r][bc]    : r*66 + bc
    __shared__ float scnt[90];
    const int tid = threadIdx.x;

    for (int i = tid; i < 90*66; i += 256) sacc[i] = 0.f;
    if (tid < 90) scnt[tid] = 0.f;

    const int bc = tid >> 2;
    const int g  = tid & 3;

    for (int ch = 0; ch < 8; ++ch) {
        const int s0 = (blockIdx.x * 8 + ch) << 7;
        __syncthreads();
        for (int idx = tid; idx < 64*128; idx += 256) {
            int bcc = idx >> 7;
            int i   = idx & 127;
            int gg  = i >> 5, kk = i & 31;
            float m = stats[2*bcc], rs = stats[2*bcc + 1];
            float v = emb[((size_t)bcc << 18) + s0 + i];
            se[bcc*132 + gg*33 + kk] = fmaxf(0.f, (v - m) * rs);
        }
        __syncthreads();

        const float* mbase  = mask + s0 + g*32;
        const float* serow  = se + bc*132 + g*33;
        for (int r = 0; r < 90; ++r) {
            const float* mp = mbase + (size_t)r * S_TOT;
            float part = 0.f, cp = 0.f;
            #pragma unroll
            for (int k = 0; k < 32; ++k) {
                float mv = mp[k];
                part = fmaf(mv, serow[k], part);
                cp  += mv;
            }
            part += __shfl_down(part, 2, 4);
            part += __shfl_down(part, 1, 4);
            cp   += __shfl_down(cp, 2, 4);
            cp   += __shfl_down(cp, 1, 4);
            if (g == 0) sacc[r*66 + bc] += part;
            if (tid == 0) scnt[r] += cp;
        }
    }
    __syncthreads();
    for (int i = tid; i < 90*64; i += 256) {
        int r = i >> 6, bcc = i & 63;
        int b = bcc >> 5, c = bcc & 31;
        atomicAdd(&roi_acc[((size_t)b*90 + r)*32 + c], sacc[r*66 + bcc]);
    }
    if (tid < 90) atomicAdd(&cnt[tid], scnt[tid]);
}

// ---------------------------------------------------------------------------
// Per-ROI gated MLP + projection. One block (64 threads) per (b, r).
// ---------------------------------------------------------------------------
__global__ __launch_bounds__(64)
void mlp_k(const float* __restrict__ roi_acc, const float* __restrict__ cnt,
           const float* __restrict__ w1, const float* __restrict__ b1,
           const float* __restrict__ w2, const float* __restrict__ b2,
           const float* __restrict__ pw1, const float* __restrict__ pb1,
           const float* __restrict__ pw2, const float* __restrict__ pb2,
           float* __restrict__ out)
{
    const int r   = blockIdx.x % 90;
    const int b   = blockIdx.x / 90;
    const int tid = threadIdx.x;
    __shared__ float roi_s[32], h_s[64], f_s[32], p_s[64];

    if (tid < 32) {
        float invc = 1.f / cnt[r];
        roi_s[tid] = roi_acc[((size_t)b*90 + r)*32 + tid] * invc;
    }
    __syncthreads();
    {
        float s = b1[r*64 + tid];
        for (int c = 0; c < 32; ++c)
            s = fmaf(roi_s[c], w1[(r*32 + c)*64 + tid], s);
        h_s[tid] = fmaxf(s, 0.f);
    }
    __syncthreads();
    if (tid < 32) {
        float s = b2[r*32 + tid];
        for (int j = 0; j < 64; ++j)
            s = fmaf(h_s[j], w2[(r*64 + j)*32 + tid], s);
        float gate = 1.f / (1.f + expf(-s));
        f_s[tid] = gate * roi_s[tid];
    }
    __syncthreads();
    {
        float s = pb1[r*64 + tid];
        for (int c = 0; c < 32; ++c)
            s = fmaf(f_s[c], pw1[(r*32 + c)*64 + tid], s);
        p_s[tid] = fmaxf(s, 0.f);
    }
    __syncthreads();
    if (tid < 32) {
        float s = pb2[r*32 + tid];
        for (int j = 0; j < 64; ++j)
            s = fmaf(p_s[j], pw2[(r*64 + j)*32 + tid], s);
        out[((size_t)b*90 + r)*32 + tid] = s;
    }
}

// ---------------------------------------------------------------------------
extern "C" void kernel_launch(void* const* d_in, const int* in_sizes, int n_in,
                              void* d_out, int out_size, void* d_ws, size_t ws_size,
                              hipStream_t stream)
{
    const float* data    = (const float*)d_in[0];
    const float* mask    = (const float*)d_in[1];
    const float* conv0_w = (const float*)d_in[2];
    const float* conv0_b = (const float*)d_in[3];
    const float* convs_w = (const float*)d_in[4];
    const float* convs_b = (const float*)d_in[5];
    const float* sw1 = (const float*)d_in[6];
    const float* sb1 = (const float*)d_in[7];
    const float* sw2 = (const float*)d_in[8];
    const float* sb2 = (const float*)d_in[9];
    const float* pw1 = (const float*)d_in[10];
    const float* pb1 = (const float*)d_in[11];
    const float* pw2 = (const float*)d_in[12];
    const float* pb2 = (const float*)d_in[13];
    float* out = (float*)d_out;

    float* ws      = (float*)d_ws;
    float* bufA    = ws;                      // 16777216 floats
    float* bufB    = ws + 16777216;           // 16777216 floats
    float* raw     = ws + 33554432;           // 512
    float* stats   = raw + 512;               // 128
    float* roi_acc = stats + 128;             // 5760
    float* cnt     = roi_acc + 5760;          // 90

    // layer 0: conv(1->32) raw
    hipLaunchKernelGGL((conv3d_k<1,false>), dim3(1024), dim3(256), 0, stream,
                       data, conv0_w, conv0_b, (const float*)nullptr, bufA);
    stats_partial_k<<<256,256,0,stream>>>(bufA, raw);
    stats_final_k<<<1,64,0,stream>>>(raw, stats);
    // layer 1
    hipLaunchKernelGGL((conv3d_k<32,true>), dim3(1024), dim3(256), 0, stream,
                       bufA, convs_w, convs_b, stats, bufB);
    stats_partial_k<<<256,256,0,stream>>>(bufB, raw);
    stats_final_k<<<1,64,0,stream>>>(raw, stats);
    // layer 2
    hipLaunchKernelGGL((conv3d_k<32,true>), dim3(1024), dim3(256), 0, stream,
                       bufB, convs_w + 27648, convs_b + 32, stats, bufA);
    stats_partial_k<<<256,256,0,stream>>>(bufA, raw);
    stats_final_k<<<1,64,0,stream>>>(raw, stats);
    // layer 3
    hipLaunchKernelGGL((conv3d_k<32,true>), dim3(1024), dim3(256), 0, stream,
                       bufA, convs_w + 2*27648, convs_b + 64, stats, bufB);
    stats_partial_k<<<256,256,0,stream>>>(bufB, raw);
    stats_final_k<<<1,64,0,stream>>>(raw, stats);

    // ROI pooling (normalize+relu of layer-3 output fused into the load)
    hipMemsetAsync(roi_acc, 0, (5760 + 90)*sizeof(float), stream);
    roi_pool_k<<<256,256,0,stream>>>(bufB, stats, mask, roi_acc, cnt);

    // per-ROI MLPs
    mlp_k<<<180,64,0,stream>>>(roi_acc, cnt, sw1, sb1, sw2, sb2,
                               pw1, pb1, pw2, pb2, out);
}

// Round 2
// 562.972 us; speedup vs baseline: 3.6067x; 3.6067x over previous
//
#include <hip/hip_runtime.h>
#include <hip/hip_bf16.h>
#include <math.h>

#define S_TOT 262144   // 64^3
#define EPS_F 1e-5f

typedef __attribute__((ext_vector_type(8))) short s16x8;
typedef __attribute__((ext_vector_type(4))) short s16x4;
typedef __attribute__((ext_vector_type(4))) float f32x4;

__device__ __forceinline__ unsigned short f2bf(float f) {
    unsigned u = __builtin_bit_cast(unsigned, f);
    unsigned r = (u + 0x7FFFu + ((u >> 16) & 1u)) >> 16;
    return (unsigned short)r;
}

// ---------------------------------------------------------------------------
// Weight prep: split fp32 weights into bf16 hi/lo, layout [layer][tap][hi/lo][cout][cin]
// layer 0: cin=1 padded to 32 with zeros.
// ---------------------------------------------------------------------------
__global__ __launch_bounds__(256)
void prep_w_k(const float* __restrict__ conv0_w, const float* __restrict__ convs_w,
              unsigned short* __restrict__ wpad)
{
    int idx = blockIdx.x * 256 + threadIdx.x;     // 4*27*32*32 = 110592
    if (idx >= 110592) return;
    int layer = idx / 27648;
    int rem   = idx - layer * 27648;
    int tap   = rem >> 10;
    int cout  = (rem >> 5) & 31;
    int cin   = rem & 31;
    float wv;
    if (layer == 0) wv = (cin == 0) ? conv0_w[cout * 27 + tap] : 0.f;
    else            wv = convs_w[(((layer - 1) * 32 + cout) * 32 + cin) * 27 + tap];
    unsigned short hi = f2bf(wv);
    float hif = __builtin_bit_cast(float, ((unsigned)hi) << 16);
    unsigned short lo = f2bf(wv - hif);
    size_t base = ((size_t)(layer * 27 + tap) * 2) * 1024 + cout * 32 + cin;
    wpad[base]        = hi;
    wpad[base + 1024] = lo;
}

// ---------------------------------------------------------------------------
// MFMA conv layer. Block: 8x8x4 spatial tile (256 voxels), 4 waves (one z-plane
// each). Wave: M=64 voxels x N=32 couts, K = 27 taps x 32 cin (hi+lo weights).
// Input: FIRST -> raw data (B,1,64,64,64); else channels-last fp32 + fused
// instance-norm+ReLU from stats_in. Output: channels-last fp32 (or channels-
// first when CFOUT, via LDS transpose). Per-(b,c) sum/sumsq accumulated into
// raw_out via shfl + LDS + atomics. Bias omitted (InstanceNorm cancels it).
// ---------------------------------------------------------------------------
template<bool FIRST, bool CFOUT>
__global__ __launch_bounds__(256)
void conv_mfma_k(const float* __restrict__ in, const unsigned short* __restrict__ wpad_l,
                 const float* __restrict__ stats_in, float* __restrict__ outb,
                 float* __restrict__ raw_out)
{
    __shared__ short lds_x[24000];     // [6 z][10 y][10 x] voxels * 40-short stride
    __shared__ float s_stat[64];       // mean[32] | rsq[32]
    __shared__ float s_red[256];       // [wave][cout][sum/sumsq]

    const int tid = threadIdx.x;
    const int blk = blockIdx.x;
    const int b   = blk >> 10;
    const int t   = blk & 1023;
    const int x0  = (t & 7) << 3;
    const int y0  = ((t >> 3) & 7) << 3;
    const int z0  = (t >> 6) << 2;

    if (!FIRST && tid < 32) {
        s_stat[tid]      = stats_in[(b * 32 + tid) * 2];
        s_stat[32 + tid] = stats_in[(b * 32 + tid) * 2 + 1];
    }
    __syncthreads();

    // ---- stage halo tile into LDS as bf16 (norm+relu fused for mid layers) ----
    if (FIRST) {
        for (int i = tid; i < 2400; i += 256) {
            int vox = i >> 2, g = i & 3;
            s16x8 vec = (s16x8)0;
            if (g == 0) {
                int zz = vox / 100, rr = vox - zz * 100, yy = rr / 10, xx = rr - yy * 10;
                int gz = z0 + zz - 1, gy = y0 + yy - 1, gx = x0 + xx - 1;
                float v = 0.f;
                if ((unsigned)gz < 64u && (unsigned)gy < 64u && (unsigned)gx < 64u)
                    v = in[((size_t)b << 18) + (gz << 12) + (gy << 6) + gx];
                vec[0] = (short)f2bf(v);
            }
            *(s16x8*)&lds_x[vox * 40 + g * 8] = vec;
        }
    } else {
        for (int i = tid; i < 2400; i += 256) {
            int vox = i >> 2, g = i & 3;
            int zz = vox / 100, rr = vox - zz * 100, yy = rr / 10, xx = rr - yy * 10;
            int gz = z0 + zz - 1, gy = y0 + yy - 1, gx = x0 + xx - 1;
            s16x8 vec;
            if ((unsigned)gz < 64u && (unsigned)gy < 64u && (unsigned)gx < 64u) {
                const float* p = in + ((((size_t)b << 18) + (gz << 12) + (gy << 6) + gx) << 5) + g * 8;
                float4 f0 = *(const float4*)p;
                float4 f1 = *(const float4*)(p + 4);
                float vv[8] = {f0.x, f0.y, f0.z, f0.w, f1.x, f1.y, f1.z, f1.w};
                #pragma unroll
                for (int j = 0; j < 8; ++j) {
                    int c = g * 8 + j;
                    float nv = fmaxf(0.f, (vv[j] - s_stat[c]) * s_stat[32 + c]);
                    vec[j] = (short)f2bf(nv);
                }
            } else vec = (s16x8)0;
            *(s16x8*)&lds_x[vox * 40 + g * 8] = vec;
        }
    }
    __syncthreads();

    // ---- MFMA main loop ----
    const int lane = tid & 63;
    const int wv   = tid >> 6;         // wave = z-plane within tile
    const int row  = lane & 15;
    const int g4   = lane >> 4;        // 0..3 (k-chunk / voxel-subrow group)

    f32x4 acc[4][2] = {};
    int abase[4];
    #pragma unroll
    for (int f = 0; f < 4; ++f) {
        int vvx = f * 16 + row;
        int xx = vvx & 7, yy = vvx >> 3;
        abase[f] = ((wv * 10 + yy) * 10 + xx) * 40 + g4 * 8;
    }

    for (int tap = 0; tap < 27; ++tap) {
        int dz = tap / 9, r9 = tap - dz * 9, dy = r9 / 3, dx = r9 - dy * 3;
        int toff = ((dz * 10 + dy) * 10 + dx) * 40;
        const unsigned short* wb = wpad_l + tap * 2048;
        s16x8 bh0 = *(const s16x8*)(wb + row * 32 + g4 * 8);
        s16x8 bh1 = *(const s16x8*)(wb + (16 + row) * 32 + g4 * 8);
        s16x8 bl0 = *(const s16x8*)(wb + 1024 + row * 32 + g4 * 8);
        s16x8 bl1 = *(const s16x8*)(wb + 1024 + (16 + row) * 32 + g4 * 8);
        #pragma unroll
        for (int f = 0; f < 4; ++f) {
            s16x8 a = *(const s16x8*)&lds_x[abase[f] + toff];
            acc[f][0] = __builtin_amdgcn_mfma_f32_16x16x32_bf16(a, bh0, acc[f][0], 0, 0, 0);
            acc[f][0] = __builtin_amdgcn_mfma_f32_16x16x32_bf16(a, bl0, acc[f][0], 0, 0, 0);
            acc[f][1] = __builtin_amdgcn_mfma_f32_16x16x32_bf16(a, bh1, acc[f][1], 0, 0, 0);
            acc[f][1] = __builtin_amdgcn_mfma_f32_16x16x32_bf16(a, bl1, acc[f][1], 0, 0, 0);
        }
    }

    // ---- fused instance-norm statistics (sum / sumsq per (b,cout)) ----
    {
        float s0 = 0.f, ss0 = 0.f, s1 = 0.f, ss1 = 0.f;
        #pragma unroll
        for (int f = 0; f < 4; ++f) {
            #pragma unroll
            for (int q = 0; q < 4; ++q) {
                float v0 = acc[f][0][q], v1 = acc[f][1][q];
                s0 += v0; ss0 += v0 * v0; s1 += v1; ss1 += v1 * v1;
            }
        }
        s0 += __shfl_xor(s0, 16); s0 += __shfl_xor(s0, 32);
        ss0 += __shfl_xor(ss0, 16); ss0 += __shfl_xor(ss0, 32);
        s1 += __shfl_xor(s1, 16); s1 += __shfl_xor(s1, 32);
        ss1 += __shfl_xor(ss1, 16); ss1 += __shfl_xor(ss1, 32);
        if (lane < 16) {
            s_red[(wv * 32 + row) * 2]          = s0;
            s_red[(wv * 32 + row) * 2 + 1]      = ss0;
            s_red[(wv * 32 + 16 + row) * 2]     = s1;
            s_red[(wv * 32 + 16 + row) * 2 + 1] = ss1;
        }
    }
    __syncthreads();
    if (tid < 64) {
        int n = tid & 31, sel = tid >> 5;
        float tot = 0.f;
        #pragma unroll
        for (int w = 0; w < 4; ++w) tot += s_red[(w * 32 + n) * 2 + sel];
        atomicAdd(&raw_out[(b * 32 + n) * 2 + sel], tot);
    }

    // ---- store ----
    if (!CFOUT) {
        #pragma unroll
        for (int f = 0; f < 4; ++f) {
            #pragma unroll
            for (int q = 0; q < 4; ++q) {
                int vvx = f * 16 + g4 * 4 + q;
                size_t base = ((((size_t)b << 18) + ((size_t)(z0 + wv) << 12)
                              + ((size_t)(y0 + (vvx >> 3)) << 6) + (x0 + (vvx & 7))) << 5);
                outb[base + row]      = acc[f][0][q];
                outb[base + 16 + row] = acc[f][1][q];
            }
        }
    } else {
        float* tr = (float*)lds_x;    // 32KB needed; lds_x is 48KB; barrier above done
        #pragma unroll
        for (int f = 0; f < 4; ++f)
            #pragma unroll
            for (int j = 0; j < 2; ++j)
                #pragma unroll
                for (int q = 0; q < 4; ++q)
                    tr[(j * 16 + row) * 256 + wv * 64 + f * 16 + g4 * 4 + q] = acc[f][j][q];
        __syncthreads();
        for (int i = tid; i < 2048; i += 256) {
            int c = i >> 6, u = i & 63;
            int vt = u * 4;
            int z = vt >> 6, yr = (vt >> 3) & 7, x = vt & 7;
            float4 v = *(const float4*)&tr[c * 256 + vt];
            *(float4*)(outb + (((size_t)(b * 32 + c)) << 18) + ((size_t)(z0 + z) << 12)
                       + ((size_t)(y0 + yr) << 6) + x0 + x) = v;
        }
    }
}

__global__ void stats_final_k(const float* __restrict__ raw, float* __restrict__ stats)
{
    int bc = threadIdx.x;   // 64
    float mean = raw[bc * 2] * (1.f / 262144.f);
    float var  = raw[bc * 2 + 1] * (1.f / 262144.f) - mean * mean;
    stats[bc * 2]     = mean;
    stats[bc * 2 + 1] = rsqrtf(var + EPS_F);
}

// ---------------------------------------------------------------------------
// Pack 0/1 float mask into bits (u64 per 64 voxels) + per-ROI voxel counts.
// ---------------------------------------------------------------------------
__global__ __launch_bounds__(256)
void pack_mask_k(const float* __restrict__ mask, unsigned long long* __restrict__ bits,
                 float* __restrict__ cnt)
{
    const int r = blockIdx.x >> 4, part = blockIdx.x & 15;
    const int lane = threadIdx.x & 63, wv = threadIdx.x >> 6;
    const size_t base = (size_t)r * S_TOT + part * 16384;
    int local = 0;
    for (int wd = wv; wd < 256; wd += 4) {
        float v = mask[base + wd * 64 + lane];
        unsigned long long bm = __ballot(v != 0.f);
        if (lane == 0) { bits[r * 4096 + part * 256 + wd] = bm; local += __popcll(bm); }
    }
    if (lane == 0) atomicAdd(&cnt[r], (float)local);
}

// ---------------------------------------------------------------------------
// ROI pooling as MFMA GEMM: D[bc=64][r=96] += A[bc][s] * B[s][r]
// A = norm+relu(emb) bf16 (emb channels-first fp32), B = mask bits -> bf16.
// 256 blocks x 8 chunks x 128 s. Partial-K accumulated via global atomics.
// ---------------------------------------------------------------------------
__global__ __launch_bounds__(256)
void pool_mfma_k(const float* __restrict__ emb, const float* __restrict__ stats3,
                 const unsigned long long* __restrict__ bits, float* __restrict__ roi_acc)
{
    __shared__ short Ald[64 * 136];   // [bc][k=128] bf16, 136-short row stride
    __shared__ short Bld[96 * 136];   // [r][k=128]  bf16

    const int tid  = threadIdx.x;
    const int lane = tid & 63, wv = tid >> 6;
    const int row  = lane & 15, g4 = lane >> 4;

    f32x4 acc[6] = {};

    for (int ch = 0; ch < 8; ++ch) {
        const int s0 = (blockIdx.x * 8 + ch) << 7;
        __syncthreads();
        // stage A: emb channels-first [bc][s] -> normalized bf16
        for (int i = tid; i < 2048; i += 256) {
            int bc = i >> 5, q = i & 31;
            float m = stats3[bc * 2], rs = stats3[bc * 2 + 1];
            float4 v = *(const float4*)(emb + ((size_t)bc << 18) + s0 + q * 4);
            s16x4 o;
            o[0] = (short)f2bf(fmaxf(0.f, (v.x - m) * rs));
            o[1] = (short)f2bf(fmaxf(0.f, (v.y - m) * rs));
            o[2] = (short)f2bf(fmaxf(0.f, (v.z - m) * rs));
            o[3] = (short)f2bf(fmaxf(0.f, (v.w - m) * rs));
            *(s16x4*)&Ald[bc * 136 + q * 4] = o;
        }
        // stage B: bit-expand mask to bf16 (r >= 90 -> zeros)
        for (int i = tid; i < 1536; i += 256) {
            int r = i >> 4, bs = i & 15;
            s16x8 vec = (s16x8)0;
            if (r < 90) {
                unsigned long long w = bits[r * 4096 + (s0 >> 6) + (bs >> 3)];
                unsigned byte = (unsigned)(w >> ((bs & 7) * 8)) & 0xFFu;
                #pragma unroll
                for (int j = 0; j < 8; ++j)
                    vec[j] = ((byte >> j) & 1u) ? (short)0x3F80 : (short)0;
            }
            *(s16x8*)&Bld[r * 136 + bs * 8] = vec;
        }
        __syncthreads();
        #pragma unroll
        for (int kk = 0; kk < 4; ++kk) {
            s16x8 a = *(const s16x8*)&Ald[(wv * 16 + row) * 136 + kk * 32 + g4 * 8];
            #pragma unroll
            for (int j = 0; j < 6; ++j) {
                s16x8 bb = *(const s16x8*)&Bld[(j * 16 + row) * 136 + kk * 32 + g4 * 8];
                acc[j] = __builtin_amdgcn_mfma_f32_16x16x32_bf16(a, bb, acc[j], 0, 0, 0);
            }
        }
    }
    #pragma unroll
    for (int j = 0; j < 6; ++j) {
        int r = j * 16 + row;
        if (r < 90) {
            #pragma unroll
            for (int q = 0; q < 4; ++q) {
                int bc = wv * 16 + g4 * 4 + q;
                atomicAdd(&roi_acc[(((bc >> 5) * 90 + r) << 5) + (bc & 31)], acc[j][q]);
            }
        }
    }
}

// ---------------------------------------------------------------------------
// Per-ROI gated MLP + projection. One block (64 threads) per (b, r).
// ---------------------------------------------------------------------------
__global__ __launch_bounds__(64)
void mlp_k(const float* __restrict__ roi_acc, const float* __restrict__ cnt,
           const float* __restrict__ w1, const float* __restrict__ b1,
           const float* __restrict__ w2, const float* __restrict__ b2,
           const float* __restrict__ pw1, const float* __restrict__ pb1,
           const float* __restrict__ pw2, const float* __restrict__ pb2,
           float* __restrict__ out)
{
    const int r   = blockIdx.x % 90;
    const int b   = blockIdx.x / 90;
    const int tid = threadIdx.x;
    __shared__ float roi_s[32], h_s[64], f_s[32], p_s[64];

    if (tid < 32) {
        float invc = 1.f / cnt[r];
        roi_s[tid] = roi_acc[((size_t)b * 90 + r) * 32 + tid] * invc;
    }
    __syncthreads();
    {
        float s = b1[r * 64 + tid];
        for (int c = 0; c < 32; ++c)
            s = fmaf(roi_s[c], w1[(r * 32 + c) * 64 + tid], s);
        h_s[tid] = fmaxf(s, 0.f);
    }
    __syncthreads();
    if (tid < 32) {
        float s = b2[r * 32 + tid];
        for (int j = 0; j < 64; ++j)
            s = fmaf(h_s[j], w2[(r * 64 + j) * 32 + tid], s);
        float gate = 1.f / (1.f + expf(-s));
        f_s[tid] = gate * roi_s[tid];
    }
    __syncthreads();
    {
        float s = pb1[r * 64 + tid];
        for (int c = 0; c < 32; ++c)
            s = fmaf(f_s[c], pw1[(r * 32 + c) * 64 + tid], s);
        p_s[tid] = fmaxf(s, 0.f);
    }
    __syncthreads();
    if (tid < 32) {
        float s = pb2[r * 32 + tid];
        for (int j = 0; j < 64; ++j)
            s = fmaf(p_s[j], pw2[(r * 64 + j) * 32 + tid], s);
        out[((size_t)b * 90 + r) * 32 + tid] = s;
    }
}

// ---------------------------------------------------------------------------
extern "C" void kernel_launch(void* const* d_in, const int* in_sizes, int n_in,
                              void* d_out, int out_size, void* d_ws, size_t ws_size,
                              hipStream_t stream)
{
    const float* data    = (const float*)d_in[0];
    const float* mask    = (const float*)d_in[1];
    const float* conv0_w = (const float*)d_in[2];
    const float* convs_w = (const float*)d_in[4];
    const float* sw1 = (const float*)d_in[6];
    const float* sb1 = (const float*)d_in[7];
    const float* sw2 = (const float*)d_in[8];
    const float* sb2 = (const float*)d_in[9];
    const float* pw1 = (const float*)d_in[10];
    const float* pb1 = (const float*)d_in[11];
    const float* pw2 = (const float*)d_in[12];
    const float* pb2 = (const float*)d_in[13];
    float* out = (float*)d_out;

    float* ws   = (float*)d_ws;
    float* bufA = ws;                         // 16,777,216 floats (channels-last acts)
    float* bufB = ws + 16777216;              // 16,777,216 floats
    unsigned short* wpad = (unsigned short*)(ws + 33554432);   // 221,184 ushort
    float* zeroreg = ws + 33554432 + 110592;  // raw[4][128] + roi_acc[5760] + cnt[90]
    float* raw     = zeroreg;                 // 512
    float* roi_acc = zeroreg + 512;           // 5760
    float* cnt     = zeroreg + 6272;          // 90
    float* stats   = zeroreg + 6362;          // [4][128]
    unsigned long long* bits = (unsigned long long*)bufA;   // 2.95MB, reused after L3

    hipMemsetAsync(zeroreg, 0, 6362 * sizeof(float), stream);
    prep_w_k<<<432, 256, 0, stream>>>(conv0_w, convs_w, wpad);

    // layer 0: data -> bufA (channels-last)
    hipLaunchKernelGGL((conv_mfma_k<true, false>), dim3(2048), dim3(256), 0, stream,
                       data, wpad, (const float*)nullptr, bufA, raw);
    stats_final_k<<<1, 64, 0, stream>>>(raw, stats);
    // layer 1: bufA -> bufB
    hipLaunchKernelGGL((conv_mfma_k<false, false>), dim3(2048), dim3(256), 0, stream,
                       bufA, wpad + 55296, stats, bufB, raw + 128);
    stats_final_k<<<1, 64, 0, stream>>>(raw + 128, stats + 128);
    // layer 2: bufB -> bufA
    hipLaunchKernelGGL((conv_mfma_k<false, false>), dim3(2048), dim3(256), 0, stream,
                       bufB, wpad + 2 * 55296, stats + 128, bufA, raw + 256);
    stats_final_k<<<1, 64, 0, stream>>>(raw + 256, stats + 256);
    // layer 3: bufA -> bufB (channels-FIRST for pooling)
    hipLaunchKernelGGL((conv_mfma_k<false, true>), dim3(2048), dim3(256), 0, stream,
                       bufA, wpad + 3 * 55296, stats + 256, bufB, raw + 384);
    stats_final_k<<<1, 64, 0, stream>>>(raw + 384, stats + 384);

    // mask -> bits (+counts); bits live in bufA which is free after layer 3
    pack_mask_k<<<1440, 256, 0, stream>>>(mask, bits, cnt);

    // ROI pooling GEMM
    pool_mfma_k<<<256, 256, 0, stream>>>(bufB, stats + 384, bits, roi_acc);

    // per-ROI MLPs
    mlp_k<<<180, 64, 0, stream>>>(roi_acc, cnt, sw1, sb1, sw2, sb2,
                                  pw1, pb1, pw2, pb2, out);
}

// Round 3
// 537.003 us; speedup vs baseline: 3.7811x; 1.0484x over previous
//
#include <hip/hip_runtime.h>
#include <hip/hip_bf16.h>
#include <math.h>

#define S_TOT 262144   // 64^3
#define EPS_F 1e-5f

typedef __attribute__((ext_vector_type(8))) short s16x8;
typedef __attribute__((ext_vector_type(4))) float f32x4;

__device__ __forceinline__ unsigned short f2bf(float f) {   // RNE, manual
    unsigned u = __builtin_bit_cast(unsigned, f);
    unsigned r = (u + 0x7FFFu + ((u >> 16) & 1u)) >> 16;
    return (unsigned short)r;
}
__device__ __forceinline__ float bf2f(unsigned short u) {
    return __builtin_bit_cast(float, ((unsigned)u) << 16);
}

// ---------------------------------------------------------------------------
// Weight prep: fp32 -> bf16 hi/lo split, layout [layer][tap][hi|lo][brow][cin],
// with INTERLEAVED cout mapping: B-row brow holds cout = 2*(brow&15)+(brow>>4),
// i.e. brow(cout) = ((cout&1)<<4) | (cout>>1).  Layer 0: cin=1 padded to 32.
// ---------------------------------------------------------------------------
__global__ __launch_bounds__(256)
void prep_w_k(const float* __restrict__ conv0_w, const float* __restrict__ convs_w,
              unsigned short* __restrict__ wpad)
{
    int idx = blockIdx.x * 256 + threadIdx.x;     // 4*27*32*32 = 110592
    if (idx >= 110592) return;
    int layer = idx / 27648;
    int rem   = idx - layer * 27648;
    int tap   = rem >> 10;
    int cout  = (rem >> 5) & 31;
    int cin   = rem & 31;
    float wv;
    if (layer == 0) wv = (cin == 0) ? conv0_w[cout * 27 + tap] : 0.f;
    else            wv = convs_w[(((layer - 1) * 32 + cout) * 32 + cin) * 27 + tap];
    unsigned short hi = f2bf(wv);
    float hif = bf2f(hi);
    unsigned short lo = f2bf(wv - hif);
    int brow = ((cout & 1) << 4) | (cout >> 1);
    size_t base = ((size_t)(layer * 27 + tap) * 2) * 1024 + brow * 32 + cin;
    wpad[base]        = hi;
    wpad[base + 1024] = lo;
}

// ---------------------------------------------------------------------------
// MFMA conv layer. Block: 512 threads (8 waves), tile 8x8x8, wave = z-plane.
// LDS tile: [10][10][10] halo voxels x 32ch bf16, dense 64B/voxel.
// Input: FIRST -> raw fp32 (B,1,64,64,64); else raw bf16 channels-last with
// fused instance-norm+ReLU on load.  Output: raw bf16 channels-last via LDS
// transpose + 16B coalesced stores.  Per-(b,cout) sum/sumsq -> raw_out atomics.
// Bias omitted (InstanceNorm cancels it).  cout = 2*row + j (interleaved).
// ---------------------------------------------------------------------------
template<bool FIRST>
__global__ __launch_bounds__(512, 4)
void conv_mfma_k(const void* __restrict__ in_, const unsigned short* __restrict__ wpad_l,
                 const float* __restrict__ stats_in, unsigned short* __restrict__ outb,
                 float* __restrict__ raw_out)
{
    __shared__ unsigned short tile[32000];   // 1000 voxels * 32ch bf16 (64B/voxel)
    __shared__ float s_red[512];             // [wave][cout][sum|sumsq]
    __shared__ float s_stat[64];             // rs[32] | -m*rs[32]

    const int tid = threadIdx.x;
    const int blk = blockIdx.x;
    const int b   = blk >> 9;
    const int t   = blk & 511;
    const int x0  = (t & 7) << 3;
    const int y0  = ((t >> 3) & 7) << 3;
    const int z0  = (t >> 6) << 3;

    if (!FIRST && tid < 32) {
        float m  = stats_in[(b * 32 + tid) * 2];
        float rs = stats_in[(b * 32 + tid) * 2 + 1];
        s_stat[tid]      = rs;
        s_stat[32 + tid] = -m * rs;
    }
    __syncthreads();

    // ---- stage halo tile (norm+relu fused for mid layers) ----
    if (FIRST) {
        const float* in = (const float*)in_;
        for (int i = tid; i < 4000; i += 512) {
            int vox = i >> 2, g = i & 3;
            s16x8 vec = (s16x8)0;
            if (g == 0) {
                int zz = vox / 100, r2 = vox - zz * 100, yy = r2 / 10, xx = r2 - yy * 10;
                int gz = z0 + zz - 1, gy = y0 + yy - 1, gx = x0 + xx - 1;
                float v = 0.f;
                if ((unsigned)gz < 64u && (unsigned)gy < 64u && (unsigned)gx < 64u)
                    v = in[((size_t)b << 18) + (gz << 12) + (gy << 6) + gx];
                vec[0] = (short)f2bf(v);
            }
            *(s16x8*)&tile[(vox << 5) + (g << 3)] = vec;
        }
    } else {
        const unsigned short* in = (const unsigned short*)in_;
        for (int i = tid; i < 4000; i += 512) {
            int vox = i >> 2, g = i & 3;
            int zz = vox / 100, r2 = vox - zz * 100, yy = r2 / 10, xx = r2 - yy * 10;
            int gz = z0 + zz - 1, gy = y0 + yy - 1, gx = x0 + xx - 1;
            s16x8 vec = (s16x8)0;
            if ((unsigned)gz < 64u && (unsigned)gy < 64u && (unsigned)gx < 64u) {
                const unsigned short* p = in
                    + ((((size_t)b << 18) + (gz << 12) + (gy << 6) + gx) << 5) + (g << 3);
                s16x8 rv = *(const s16x8*)p;
                #pragma unroll
                for (int j = 0; j < 8; ++j) {
                    int c = (g << 3) + j;
                    float v  = bf2f((unsigned short)rv[j]);
                    float nv = fmaxf(0.f, fmaf(v, s_stat[c], s_stat[32 + c]));
                    vec[j] = (short)f2bf(nv);
                }
            }
            *(s16x8*)&tile[(vox << 5) + (g << 3)] = vec;
        }
    }
    __syncthreads();

    // ---- MFMA main loop (27 taps, weight prefetch +1) ----
    const int lane = tid & 63;
    const int wv   = tid >> 6;          // z-plane 0..7
    const int row  = lane & 15;
    const int g4   = lane >> 4;

    int vbase[4];
    #pragma unroll
    for (int f = 0; f < 4; ++f) {
        int vvx = f * 16 + row;
        vbase[f] = wv * 100 + (vvx >> 3) * 10 + (vvx & 7);
    }

    f32x4 acc[4][2] = {};
    s16x8 wh0 = *(const s16x8*)(wpad_l + row * 32 + g4 * 8);
    s16x8 wh1 = *(const s16x8*)(wpad_l + (16 + row) * 32 + g4 * 8);
    s16x8 wl0 = *(const s16x8*)(wpad_l + 1024 + row * 32 + g4 * 8);
    s16x8 wl1 = *(const s16x8*)(wpad_l + 1024 + (16 + row) * 32 + g4 * 8);

    #pragma unroll 1
    for (int tap = 0; tap < 27; ++tap) {
        int ntap = (tap < 26) ? tap + 1 : 26;
        const unsigned short* wn = wpad_l + ntap * 2048;
        s16x8 nh0 = *(const s16x8*)(wn + row * 32 + g4 * 8);
        s16x8 nh1 = *(const s16x8*)(wn + (16 + row) * 32 + g4 * 8);
        s16x8 nl0 = *(const s16x8*)(wn + 1024 + row * 32 + g4 * 8);
        s16x8 nl1 = *(const s16x8*)(wn + 1024 + (16 + row) * 32 + g4 * 8);

        int dz = tap / 9, r9 = tap - dz * 9, dy = r9 / 3, dx = r9 - dy * 3;
        int dvox = dz * 100 + dy * 10 + dx;
        #pragma unroll
        for (int f = 0; f < 4; ++f) {
            s16x8 a = *(const s16x8*)&tile[((vbase[f] + dvox) << 5) + (g4 << 3)];
            acc[f][0] = __builtin_amdgcn_mfma_f32_16x16x32_bf16(a, wh0, acc[f][0], 0, 0, 0);
            acc[f][0] = __builtin_amdgcn_mfma_f32_16x16x32_bf16(a, wl0, acc[f][0], 0, 0, 0);
            acc[f][1] = __builtin_amdgcn_mfma_f32_16x16x32_bf16(a, wh1, acc[f][1], 0, 0, 0);
            acc[f][1] = __builtin_amdgcn_mfma_f32_16x16x32_bf16(a, wl1, acc[f][1], 0, 0, 0);
        }
        wh0 = nh0; wh1 = nh1; wl0 = nl0; wl1 = nl1;
    }

    // ---- instance-norm partial stats (per b,cout) ----
    {
        float s0 = 0.f, ss0 = 0.f, s1 = 0.f, ss1 = 0.f;
        #pragma unroll
        for (int f = 0; f < 4; ++f) {
            #pragma unroll
            for (int q = 0; q < 4; ++q) {
                float v0 = acc[f][0][q], v1 = acc[f][1][q];
                s0 += v0; ss0 += v0 * v0; s1 += v1; ss1 += v1 * v1;
            }
        }
        s0 += __shfl_xor(s0, 16); s0 += __shfl_xor(s0, 32);
        ss0 += __shfl_xor(ss0, 16); ss0 += __shfl_xor(ss0, 32);
        s1 += __shfl_xor(s1, 16); s1 += __shfl_xor(s1, 32);
        ss1 += __shfl_xor(ss1, 16); ss1 += __shfl_xor(ss1, 32);
        if (lane < 16) {
            s_red[(wv * 32 + 2 * row) * 2]         = s0;
            s_red[(wv * 32 + 2 * row) * 2 + 1]     = ss0;
            s_red[(wv * 32 + 2 * row + 1) * 2]     = s1;
            s_red[(wv * 32 + 2 * row + 1) * 2 + 1] = ss1;
        }
    }
    __syncthreads();   // tile free for transpose, s_red complete

    // ---- transpose acc -> [vox][ch] bf16 in LDS (channel pairs packed b32) ----
    unsigned short* tr = tile;     // 512 vox * 32ch = 16384 shorts
    #pragma unroll
    for (int f = 0; f < 4; ++f) {
        #pragma unroll
        for (int q = 0; q < 4; ++q) {
            int vox = wv * 64 + f * 16 + g4 * 4 + q;
            unsigned pk = (unsigned)f2bf(acc[f][0][q]) | ((unsigned)f2bf(acc[f][1][q]) << 16);
            *(unsigned*)&tr[(vox << 5) + (row << 1)] = pk;
        }
    }
    __syncthreads();

    // ---- stats atomics + coalesced bf16 store ----
    if (tid < 64) {
        int n = tid & 31, sel = tid >> 5;
        float tot = 0.f;
        #pragma unroll
        for (int w = 0; w < 8; ++w) tot += s_red[(w * 32 + n) * 2 + sel];
        atomicAdd(&raw_out[(b * 32 + n) * 2 + sel], tot);
    }
    for (int i = tid; i < 2048; i += 512) {
        int vox = i >> 2, c16 = i & 3;
        int zz = vox >> 6, yy = (vox >> 3) & 7, xx = vox & 7;
        s16x8 v = *(const s16x8*)&tr[(vox << 5) + (c16 << 3)];
        size_t gb = ((((size_t)b << 18) + ((size_t)(z0 + zz) << 12)
                    + ((y0 + yy) << 6) + (x0 + xx)) << 5) + (c16 << 3);
        *(s16x8*)(outb + gb) = v;
    }
}

__global__ void stats_final_k(const float* __restrict__ raw, float* __restrict__ stats)
{
    int bc = threadIdx.x;   // 64
    float mean = raw[bc * 2] * (1.f / 262144.f);
    float var  = raw[bc * 2 + 1] * (1.f / 262144.f) - mean * mean;
    stats[bc * 2]     = mean;
    stats[bc * 2 + 1] = rsqrtf(var + EPS_F);
}

// ---------------------------------------------------------------------------
// Pack 0/1 float mask into bits (u64 per 64 voxels) + per-ROI voxel counts.
// ---------------------------------------------------------------------------
__global__ __launch_bounds__(256)
void pack_mask_k(const float* __restrict__ mask, unsigned long long* __restrict__ bits,
                 float* __restrict__ cnt)
{
    const int r = blockIdx.x >> 4, part = blockIdx.x & 15;
    const int lane = threadIdx.x & 63, wv = threadIdx.x >> 6;
    const size_t base = (size_t)r * S_TOT + part * 16384;
    int local = 0;
    for (int wd = wv; wd < 256; wd += 4) {
        float v = mask[base + wd * 64 + lane];
        unsigned long long bm = __ballot(v != 0.f);
        if (lane == 0) { bits[r * 4096 + part * 256 + wd] = bm; local += __popcll(bm); }
    }
    if (lane == 0) atomicAdd(&cnt[r], (float)local);
}

// ---------------------------------------------------------------------------
// ROI pooling as MFMA GEMM: D[bc=64][r=96] += A[bc][s] * B[s][r]
// A = norm+relu(emb bf16 channels-last), transposed into LDS on load.
// B = mask bits -> bf16.  1024 blocks x 2 chunks x 128 s; atomics accumulate.
// ---------------------------------------------------------------------------
__global__ __launch_bounds__(256)
void pool_mfma_k(const unsigned short* __restrict__ emb, const float* __restrict__ stats3,
                 const unsigned long long* __restrict__ bits, float* __restrict__ roi_acc)
{
    __shared__ unsigned short Ald[64 * 136];   // [bc][k=128] bf16
    __shared__ unsigned short Bld[96 * 136];   // [r][k=128] bf16
    __shared__ float s_ns[128];                // rs[64] | -m*rs[64]

    const int tid  = threadIdx.x;
    const int lane = tid & 63, wv = tid >> 6;
    const int row  = lane & 15, g4 = lane >> 4;

    if (tid < 64) {
        float m = stats3[tid * 2], rs = stats3[tid * 2 + 1];
        s_ns[tid]      = rs;
        s_ns[64 + tid] = -m * rs;
    }

    f32x4 acc[6] = {};

    for (int ch = 0; ch < 2; ++ch) {
        const int s0 = (blockIdx.x * 2 + ch) << 7;
        __syncthreads();
        // stage A: channels-last bf16 -> normalized [bc][s] (transpose on load)
        for (int i = tid; i < 1024; i += 256) {
            int bb = i >> 9, v = (i >> 2) & 127, g = i & 3;
            const unsigned short* p = emb + (((size_t)bb << 18) + (size_t)(s0 + v)) * 32 + (g << 3);
            s16x8 rv = *(const s16x8*)p;
            #pragma unroll
            for (int j = 0; j < 8; ++j) {
                int bc = bb * 32 + (g << 3) + j;
                float vf = bf2f((unsigned short)rv[j]);
                float nv = fmaxf(0.f, fmaf(vf, s_ns[bc], s_ns[64 + bc]));
                Ald[bc * 136 + v] = f2bf(nv);
            }
        }
        // stage B: bit-expand mask to bf16 (r >= 90 -> zeros)
        for (int i = tid; i < 1536; i += 256) {
            int r = i >> 4, bs = i & 15;
            s16x8 vec = (s16x8)0;
            if (r < 90) {
                unsigned long long w = bits[r * 4096 + (s0 >> 6) + (bs >> 3)];
                unsigned byte = (unsigned)(w >> ((bs & 7) * 8)) & 0xFFu;
                #pragma unroll
                for (int j = 0; j < 8; ++j)
                    vec[j] = ((byte >> j) & 1u) ? (short)0x3F80 : (short)0;
            }
            *(s16x8*)&Bld[r * 136 + bs * 8] = vec;
        }
        __syncthreads();
        #pragma unroll
        for (int kk = 0; kk < 4; ++kk) {
            s16x8 a = *(const s16x8*)&Ald[(wv * 16 + row) * 136 + kk * 32 + g4 * 8];
            #pragma unroll
            for (int j = 0; j < 6; ++j) {
                s16x8 bb = *(const s16x8*)&Bld[(j * 16 + row) * 136 + kk * 32 + g4 * 8];
                acc[j] = __builtin_amdgcn_mfma_f32_16x16x32_bf16(a, bb, acc[j], 0, 0, 0);
            }
        }
    }
    #pragma unroll
    for (int j = 0; j < 6; ++j) {
        int r = j * 16 + row;
        if (r < 90) {
            #pragma unroll
            for (int q = 0; q < 4; ++q) {
                int bc = wv * 16 + g4 * 4 + q;
                atomicAdd(&roi_acc[(((bc >> 5) * 90 + r) << 5) + (bc & 31)], acc[j][q]);
            }
        }
    }
}

// ---------------------------------------------------------------------------
// Per-ROI gated MLP + projection. One block (64 threads) per (b, r).
// ---------------------------------------------------------------------------
__global__ __launch_bounds__(64)
void mlp_k(const float* __restrict__ roi_acc, const float* __restrict__ cnt,
           const float* __restrict__ w1, const float* __restrict__ b1,
           const float* __restrict__ w2, const float* __restrict__ b2,
           const float* __restrict__ pw1, const float* __restrict__ pb1,
           const float* __restrict__ pw2, const float* __restrict__ pb2,
           float* __restrict__ out)
{
    const int r   = blockIdx.x % 90;
    const int b   = blockIdx.x / 90;
    const int tid = threadIdx.x;
    __shared__ float roi_s[32], h_s[64], f_s[32], p_s[64];

    if (tid < 32) {
        float invc = 1.f / cnt[r];
        roi_s[tid] = roi_acc[((size_t)b * 90 + r) * 32 + tid] * invc;
    }
    __syncthreads();
    {
        float s = b1[r * 64 + tid];
        for (int c = 0; c < 32; ++c)
            s = fmaf(roi_s[c], w1[(r * 32 + c) * 64 + tid], s);
        h_s[tid] = fmaxf(s, 0.f);
    }
    __syncthreads();
    if (tid < 32) {
        float s = b2[r * 32 + tid];
        for (int j = 0; j < 64; ++j)
            s = fmaf(h_s[j], w2[(r * 64 + j) * 32 + tid], s);
        float gate = 1.f / (1.f + expf(-s));
        f_s[tid] = gate * roi_s[tid];
    }
    __syncthreads();
    {
        float s = pb1[r * 64 + tid];
        for (int c = 0; c < 32; ++c)
            s = fmaf(f_s[c], pw1[(r * 32 + c) * 64 + tid], s);
        p_s[tid] = fmaxf(s, 0.f);
    }
    __syncthreads();
    if (tid < 32) {
        float s = pb2[r * 32 + tid];
        for (int j = 0; j < 64; ++j)
            s = fmaf(p_s[j], pw2[(r * 64 + j) * 32 + tid], s);
        out[((size_t)b * 90 + r) * 32 + tid] = s;
    }
}

// ---------------------------------------------------------------------------
extern "C" void kernel_launch(void* const* d_in, const int* in_sizes, int n_in,
                              void* d_out, int out_size, void* d_ws, size_t ws_size,
                              hipStream_t stream)
{
    const float* data    = (const float*)d_in[0];
    const float* mask    = (const float*)d_in[1];
    const float* conv0_w = (const float*)d_in[2];
    const float* convs_w = (const float*)d_in[4];
    const float* sw1 = (const float*)d_in[6];
    const float* sb1 = (const float*)d_in[7];
    const float* sw2 = (const float*)d_in[8];
    const float* sb2 = (const float*)d_in[9];
    const float* pw1 = (const float*)d_in[10];
    const float* pb1 = (const float*)d_in[11];
    const float* pw2 = (const float*)d_in[12];
    const float* pb2 = (const float*)d_in[13];
    float* out = (float*)d_out;

    float* ws = (float*)d_ws;
    unsigned short* bufA = (unsigned short*)ws;                  // 16,777,216 bf16
    unsigned short* bufB = (unsigned short*)(ws + 8388608);      // 16,777,216 bf16
    unsigned short* wpad = (unsigned short*)(ws + 16777216);     // 221,184 ushort
    float* zeroreg = ws + 16887808;
    float* raw     = zeroreg;            // 512
    float* roi_acc = zeroreg + 512;      // 5760
    float* cnt     = zeroreg + 6272;     // 90
    float* stats   = zeroreg + 6362;     // 512
    unsigned long long* bits = (unsigned long long*)(ws + 16894720);  // 368,640 u64

    hipMemsetAsync(zeroreg, 0, 6362 * sizeof(float), stream);
    prep_w_k<<<432, 256, 0, stream>>>(conv0_w, convs_w, wpad);

    // layer 0: data(fp32) -> bufA (bf16 channels-last)
    hipLaunchKernelGGL((conv_mfma_k<true>), dim3(1024), dim3(512), 0, stream,
                       (const void*)data, wpad, (const float*)nullptr, bufA, raw);
    stats_final_k<<<1, 64, 0, stream>>>(raw, stats);
    // layer 1: bufA -> bufB
    hipLaunchKernelGGL((conv_mfma_k<false>), dim3(1024), dim3(512), 0, stream,
                       (const void*)bufA, wpad + 55296, stats, bufB, raw + 128);
    stats_final_k<<<1, 64, 0, stream>>>(raw + 128, stats + 128);
    // layer 2: bufB -> bufA
    hipLaunchKernelGGL((conv_mfma_k<false>), dim3(1024), dim3(512), 0, stream,
                       (const void*)bufB, wpad + 2 * 55296, stats + 128, bufA, raw + 256);
    stats_final_k<<<1, 64, 0, stream>>>(raw + 256, stats + 256);
    // layer 3: bufA -> bufB (bf16 channels-last)
    hipLaunchKernelGGL((conv_mfma_k<false>), dim3(1024), dim3(512), 0, stream,
                       (const void*)bufA, wpad + 3 * 55296, stats + 256, bufB, raw + 384);
    stats_final_k<<<1, 64, 0, stream>>>(raw + 384, stats + 384);

    // mask -> bits (+counts)
    pack_mask_k<<<1440, 256, 0, stream>>>(mask, bits, cnt);

    // ROI pooling GEMM (emb = bufB, norm fused on load)
    pool_mfma_k<<<1024, 256, 0, stream>>>(bufB, stats + 384, bits, roi_acc);

    // per-ROI MLPs
    mlp_k<<<180, 64, 0, stream>>>(roi_acc, cnt, sw1, sb1, sw2, sb2,
                                  pw1, pb1, pw2, pb2, out);
}

// Round 4
// 458.842 us; speedup vs baseline: 4.4252x; 1.1703x over previous
//
#include <hip/hip_runtime.h>
#include <hip/hip_bf16.h>
#include <math.h>

#define S_TOT 262144   // 64^3
#define EPS_F 1e-5f
#define NPART 1024     // pool partial-K blocks

typedef __attribute__((ext_vector_type(8))) short s16x8;
typedef __attribute__((ext_vector_type(4))) float f32x4;

__device__ __forceinline__ unsigned short f2bf(float f) {   // RNE, manual
    unsigned u = __builtin_bit_cast(unsigned, f);
    unsigned r = (u + 0x7FFFu + ((u >> 16) & 1u)) >> 16;
    return (unsigned short)r;
}
__device__ __forceinline__ float bf2f(unsigned short u) {
    return __builtin_bit_cast(float, ((unsigned)u) << 16);
}

// ---------------------------------------------------------------------------
// Weight prep: fp32 -> bf16 hi/lo split, layout [layer][tap][hi|lo][brow][cin],
// with INTERLEAVED cout mapping: B-row brow holds cout = 2*(brow&15)+(brow>>4),
// i.e. brow(cout) = ((cout&1)<<4) | (cout>>1).  Layer 0: cin=1 padded to 32.
// ---------------------------------------------------------------------------
__global__ __launch_bounds__(256)
void prep_w_k(const float* __restrict__ conv0_w, const float* __restrict__ convs_w,
              unsigned short* __restrict__ wpad)
{
    int idx = blockIdx.x * 256 + threadIdx.x;     // 4*27*32*32 = 110592
    if (idx >= 110592) return;
    int layer = idx / 27648;
    int rem   = idx - layer * 27648;
    int tap   = rem >> 10;
    int cout  = (rem >> 5) & 31;
    int cin   = rem & 31;
    float wv;
    if (layer == 0) wv = (cin == 0) ? conv0_w[cout * 27 + tap] : 0.f;
    else            wv = convs_w[(((layer - 1) * 32 + cout) * 32 + cin) * 27 + tap];
    unsigned short hi = f2bf(wv);
    float hif = bf2f(hi);
    unsigned short lo = f2bf(wv - hif);
    int brow = ((cout & 1) << 4) | (cout >> 1);
    size_t base = ((size_t)(layer * 27 + tap) * 2) * 1024 + brow * 32 + cin;
    wpad[base]        = hi;
    wpad[base + 1024] = lo;
}

// ---------------------------------------------------------------------------
// MFMA conv layer. Block: 512 threads (8 waves), tile 8x8x8, wave = z-plane.
// LDS tile: [10][10][10] halo voxels x 32ch bf16, dense 64B/voxel.
// Input: FIRST -> raw fp32 (B,1,64,64,64); else raw bf16 channels-last with
// fused instance-norm+ReLU on load.  Output: raw bf16 channels-last via LDS
// transpose + 16B coalesced stores.  Per-(b,cout) sum/sumsq -> raw_out atomics.
// Bias omitted (InstanceNorm cancels it).  cout = 2*row + j (interleaved).
// ---------------------------------------------------------------------------
template<bool FIRST>
__global__ __launch_bounds__(512, 4)
void conv_mfma_k(const void* __restrict__ in_, const unsigned short* __restrict__ wpad_l,
                 const float* __restrict__ stats_in, unsigned short* __restrict__ outb,
                 float* __restrict__ raw_out)
{
    __shared__ unsigned short tile[32000];   // 1000 voxels * 32ch bf16 (64B/voxel)
    __shared__ float s_red[512];             // [wave][cout][sum|sumsq]
    __shared__ float s_stat[64];             // rs[32] | -m*rs[32]

    const int tid = threadIdx.x;
    const int blk = blockIdx.x;
    const int b   = blk >> 9;
    const int t   = blk & 511;
    const int x0  = (t & 7) << 3;
    const int y0  = ((t >> 3) & 7) << 3;
    const int z0  = (t >> 6) << 3;

    if (!FIRST && tid < 32) {
        float m  = stats_in[(b * 32 + tid) * 2];
        float rs = stats_in[(b * 32 + tid) * 2 + 1];
        s_stat[tid]      = rs;
        s_stat[32 + tid] = -m * rs;
    }
    __syncthreads();

    // ---- stage halo tile (norm+relu fused for mid layers) ----
    if (FIRST) {
        const float* in = (const float*)in_;
        for (int i = tid; i < 4000; i += 512) {
            int vox = i >> 2, g = i & 3;
            s16x8 vec = (s16x8)0;
            if (g == 0) {
                int zz = vox / 100, r2 = vox - zz * 100, yy = r2 / 10, xx = r2 - yy * 10;
                int gz = z0 + zz - 1, gy = y0 + yy - 1, gx = x0 + xx - 1;
                float v = 0.f;
                if ((unsigned)gz < 64u && (unsigned)gy < 64u && (unsigned)gx < 64u)
                    v = in[((size_t)b << 18) + (gz << 12) + (gy << 6) + gx];
                vec[0] = (short)f2bf(v);
            }
            *(s16x8*)&tile[(vox << 5) + (g << 3)] = vec;
        }
    } else {
        const unsigned short* in = (const unsigned short*)in_;
        for (int i = tid; i < 4000; i += 512) {
            int vox = i >> 2, g = i & 3;
            int zz = vox / 100, r2 = vox - zz * 100, yy = r2 / 10, xx = r2 - yy * 10;
            int gz = z0 + zz - 1, gy = y0 + yy - 1, gx = x0 + xx - 1;
            s16x8 vec = (s16x8)0;
            if ((unsigned)gz < 64u && (unsigned)gy < 64u && (unsigned)gx < 64u) {
                const unsigned short* p = in
                    + ((((size_t)b << 18) + (gz << 12) + (gy << 6) + gx) << 5) + (g << 3);
                s16x8 rv = *(const s16x8*)p;
                #pragma unroll
                for (int j = 0; j < 8; ++j) {
                    int c = (g << 3) + j;
                    float v  = bf2f((unsigned short)rv[j]);
                    float nv = fmaxf(0.f, fmaf(v, s_stat[c], s_stat[32 + c]));
                    vec[j] = (short)f2bf(nv);
                }
            }
            *(s16x8*)&tile[(vox << 5) + (g << 3)] = vec;
        }
    }
    __syncthreads();

    // ---- MFMA main loop (27 taps, weight prefetch +1) ----
    const int lane = tid & 63;
    const int wv   = tid >> 6;          // z-plane 0..7
    const int row  = lane & 15;
    const int g4   = lane >> 4;

    int vbase[4];
    #pragma unroll
    for (int f = 0; f < 4; ++f) {
        int vvx = f * 16 + row;
        vbase[f] = wv * 100 + (vvx >> 3) * 10 + (vvx & 7);
    }

    f32x4 acc[4][2] = {};
    s16x8 wh0 = *(const s16x8*)(wpad_l + row * 32 + g4 * 8);
    s16x8 wh1 = *(const s16x8*)(wpad_l + (16 + row) * 32 + g4 * 8);
    s16x8 wl0 = *(const s16x8*)(wpad_l + 1024 + row * 32 + g4 * 8);
    s16x8 wl1 = *(const s16x8*)(wpad_l + 1024 + (16 + row) * 32 + g4 * 8);

    #pragma unroll 1
    for (int tap = 0; tap < 27; ++tap) {
        int ntap = (tap < 26) ? tap + 1 : 26;
        const unsigned short* wn = wpad_l + ntap * 2048;
        s16x8 nh0 = *(const s16x8*)(wn + row * 32 + g4 * 8);
        s16x8 nh1 = *(const s16x8*)(wn + (16 + row) * 32 + g4 * 8);
        s16x8 nl0 = *(const s16x8*)(wn + 1024 + row * 32 + g4 * 8);
        s16x8 nl1 = *(const s16x8*)(wn + 1024 + (16 + row) * 32 + g4 * 8);

        int dz = tap / 9, r9 = tap - dz * 9, dy = r9 / 3, dx = r9 - dy * 3;
        int dvox = dz * 100 + dy * 10 + dx;
        #pragma unroll
        for (int f = 0; f < 4; ++f) {
            s16x8 a = *(const s16x8*)&tile[((vbase[f] + dvox) << 5) + (g4 << 3)];
            acc[f][0] = __builtin_amdgcn_mfma_f32_16x16x32_bf16(a, wh0, acc[f][0], 0, 0, 0);
            acc[f][0] = __builtin_amdgcn_mfma_f32_16x16x32_bf16(a, wl0, acc[f][0], 0, 0, 0);
            acc[f][1] = __builtin_amdgcn_mfma_f32_16x16x32_bf16(a, wh1, acc[f][1], 0, 0, 0);
            acc[f][1] = __builtin_amdgcn_mfma_f32_16x16x32_bf16(a, wl1, acc[f][1], 0, 0, 0);
        }
        wh0 = nh0; wh1 = nh1; wl0 = nl0; wl1 = nl1;
    }

    // ---- instance-norm partial stats (per b,cout) ----
    {
        float s0 = 0.f, ss0 = 0.f, s1 = 0.f, ss1 = 0.f;
        #pragma unroll
        for (int f = 0; f < 4; ++f) {
            #pragma unroll
            for (int q = 0; q < 4; ++q) {
                float v0 = acc[f][0][q], v1 = acc[f][1][q];
                s0 += v0; ss0 += v0 * v0; s1 += v1; ss1 += v1 * v1;
            }
        }
        s0 += __shfl_xor(s0, 16); s0 += __shfl_xor(s0, 32);
        ss0 += __shfl_xor(ss0, 16); ss0 += __shfl_xor(ss0, 32);
        s1 += __shfl_xor(s1, 16); s1 += __shfl_xor(s1, 32);
        ss1 += __shfl_xor(ss1, 16); ss1 += __shfl_xor(ss1, 32);
        if (lane < 16) {
            s_red[(wv * 32 + 2 * row) * 2]         = s0;
            s_red[(wv * 32 + 2 * row) * 2 + 1]     = ss0;
            s_red[(wv * 32 + 2 * row + 1) * 2]     = s1;
            s_red[(wv * 32 + 2 * row + 1) * 2 + 1] = ss1;
        }
    }
    __syncthreads();   // tile free for transpose, s_red complete

    // ---- transpose acc -> [vox][ch] bf16 in LDS (channel pairs packed b32) ----
    unsigned short* tr = tile;     // 512 vox * 32ch = 16384 shorts
    #pragma unroll
    for (int f = 0; f < 4; ++f) {
        #pragma unroll
        for (int q = 0; q < 4; ++q) {
            int vox = wv * 64 + f * 16 + g4 * 4 + q;
            unsigned pk = (unsigned)f2bf(acc[f][0][q]) | ((unsigned)f2bf(acc[f][1][q]) << 16);
            *(unsigned*)&tr[(vox << 5) + (row << 1)] = pk;
        }
    }
    __syncthreads();

    // ---- stats atomics + coalesced bf16 store ----
    if (tid < 64) {
        int n = tid & 31, sel = tid >> 5;
        float tot = 0.f;
        #pragma unroll
        for (int w = 0; w < 8; ++w) tot += s_red[(w * 32 + n) * 2 + sel];
        atomicAdd(&raw_out[(b * 32 + n) * 2 + sel], tot);
    }
    for (int i = tid; i < 2048; i += 512) {
        int vox = i >> 2, c16 = i & 3;
        int zz = vox >> 6, yy = (vox >> 3) & 7, xx = vox & 7;
        s16x8 v = *(const s16x8*)&tr[(vox << 5) + (c16 << 3)];
        size_t gb = ((((size_t)b << 18) + ((size_t)(z0 + zz) << 12)
                    + ((y0 + yy) << 6) + (x0 + xx)) << 5) + (c16 << 3);
        *(s16x8*)(outb + gb) = v;
    }
}

__global__ void stats_final_k(const float* __restrict__ raw, float* __restrict__ stats)
{
    int bc = threadIdx.x;   // 64
    float mean = raw[bc * 2] * (1.f / 262144.f);
    float var  = raw[bc * 2 + 1] * (1.f / 262144.f) - mean * mean;
    stats[bc * 2]     = mean;
    stats[bc * 2 + 1] = rsqrtf(var + EPS_F);
}

// ---------------------------------------------------------------------------
// Pack 0/1 float mask into bits (u64 per 64 voxels) + per-ROI voxel counts.
// ---------------------------------------------------------------------------
__global__ __launch_bounds__(256)
void pack_mask_k(const float* __restrict__ mask, unsigned long long* __restrict__ bits,
                 float* __restrict__ cnt)
{
    const int r = blockIdx.x >> 4, part = blockIdx.x & 15;
    const int lane = threadIdx.x & 63, wv = threadIdx.x >> 6;
    const size_t base = (size_t)r * S_TOT + part * 16384;
    int local = 0;
    for (int wd = wv; wd < 256; wd += 4) {
        float v = mask[base + wd * 64 + lane];
        unsigned long long bm = __ballot(v != 0.f);
        if (lane == 0) { bits[r * 4096 + part * 256 + wd] = bm; local += __popcll(bm); }
    }
    if (lane == 0) atomicAdd(&cnt[r], (float)local);
}

// ---------------------------------------------------------------------------
// ROI pooling as MFMA GEMM: D[bc=64][r=96] += A[bc][s] * B[s][r]
// A = norm+relu(emb bf16 channels-last), transposed into LDS on load.
// B = mask bits -> bf16.  NPART blocks x 2 chunks x 128 s.
// Epilogue: DENSE per-block partial tile store (no atomics) to
// part[block][96][64] — reduced later inside mlp_k.
// ---------------------------------------------------------------------------
__global__ __launch_bounds__(256)
void pool_mfma_k(const unsigned short* __restrict__ emb, const float* __restrict__ stats3,
                 const unsigned long long* __restrict__ bits, float* __restrict__ part)
{
    __shared__ unsigned short Ald[64 * 136];   // [bc][k=128] bf16
    __shared__ unsigned short Bld[96 * 136];   // [r][k=128] bf16
    __shared__ float s_ns[128];                // rs[64] | -m*rs[64]

    const int tid  = threadIdx.x;
    const int lane = tid & 63, wv = tid >> 6;
    const int row  = lane & 15, g4 = lane >> 4;

    if (tid < 64) {
        float m = stats3[tid * 2], rs = stats3[tid * 2 + 1];
        s_ns[tid]      = rs;
        s_ns[64 + tid] = -m * rs;
    }

    f32x4 acc[6] = {};

    for (int ch = 0; ch < 2; ++ch) {
        const int s0 = (blockIdx.x * 2 + ch) << 7;
        __syncthreads();
        // stage A: channels-last bf16 -> normalized [bc][s] (transpose on load)
        for (int i = tid; i < 1024; i += 256) {
            int bb = i >> 9, v = (i >> 2) & 127, g = i & 3;
            const unsigned short* p = emb + (((size_t)bb << 18) + (size_t)(s0 + v)) * 32 + (g << 3);
            s16x8 rv = *(const s16x8*)p;
            #pragma unroll
            for (int j = 0; j < 8; ++j) {
                int bc = bb * 32 + (g << 3) + j;
                float vf = bf2f((unsigned short)rv[j]);
                float nv = fmaxf(0.f, fmaf(vf, s_ns[bc], s_ns[64 + bc]));
                Ald[bc * 136 + v] = f2bf(nv);
            }
        }
        // stage B: bit-expand mask to bf16 (r >= 90 -> zeros)
        for (int i = tid; i < 1536; i += 256) {
            int r = i >> 4, bs = i & 15;
            s16x8 vec = (s16x8)0;
            if (r < 90) {
                unsigned long long w = bits[r * 4096 + (s0 >> 6) + (bs >> 3)];
                unsigned byte = (unsigned)(w >> ((bs & 7) * 8)) & 0xFFu;
                #pragma unroll
                for (int j = 0; j < 8; ++j)
                    vec[j] = ((byte >> j) & 1u) ? (short)0x3F80 : (short)0;
            }
            *(s16x8*)&Bld[r * 136 + bs * 8] = vec;
        }
        __syncthreads();
        #pragma unroll
        for (int kk = 0; kk < 4; ++kk) {
            s16x8 a = *(const s16x8*)&Ald[(wv * 16 + row) * 136 + kk * 32 + g4 * 8];
            #pragma unroll
            for (int j = 0; j < 6; ++j) {
                s16x8 bb = *(const s16x8*)&Bld[(j * 16 + row) * 136 + kk * 32 + g4 * 8];
                acc[j] = __builtin_amdgcn_mfma_f32_16x16x32_bf16(a, bb, acc[j], 0, 0, 0);
            }
        }
    }
    // dense partial store: part[blk][r][bc], 16B per (j): bc base = wv*16+g4*4
    #pragma unroll
    for (int j = 0; j < 6; ++j) {
        *(f32x4*)&part[((size_t)blockIdx.x * 96 + j * 16 + row) * 64 + wv * 16 + g4 * 4]
            = acc[j];
    }
}

// ---------------------------------------------------------------------------
// Per-ROI partial reduction + gated MLP + projection. One block (64 threads)
// per (b, r).  Prologue sums the NPART pool partials (2 threads per channel,
// coalesced strided reads), then the tiny MLP chain as before.
// ---------------------------------------------------------------------------
__global__ __launch_bounds__(64)
void mlp_k(const float* __restrict__ part, const float* __restrict__ cnt,
           const float* __restrict__ w1, const float* __restrict__ b1,
           const float* __restrict__ w2, const float* __restrict__ b2,
           const float* __restrict__ pw1, const float* __restrict__ pb1,
           const float* __restrict__ pw2, const float* __restrict__ pb2,
           float* __restrict__ out)
{
    const int r   = blockIdx.x % 90;
    const int b   = blockIdx.x / 90;
    const int tid = threadIdx.x;
    __shared__ float roi_s[32], h_s[64], f_s[32], p_s[64];

    // ---- reduce NPART partials: c = tid&31, half h = tid>>5 sums NPART/2 ----
    {
        const int c = tid & 31, h = tid >> 5;
        const float* pp = part + ((size_t)(h * (NPART / 2)) * 96 + r) * 64 + b * 32 + c;
        float s = 0.f;
        #pragma unroll 4
        for (int p = 0; p < NPART / 2; ++p) s += pp[(size_t)p * 6144];
        s += __shfl_down(s, 32);
        if (tid < 32) roi_s[tid] = s / cnt[r];
    }
    __syncthreads();
    {
        float s = b1[r * 64 + tid];
        for (int c = 0; c < 32; ++c)
            s = fmaf(roi_s[c], w1[(r * 32 + c) * 64 + tid], s);
        h_s[tid] = fmaxf(s, 0.f);
    }
    __syncthreads();
    if (tid < 32) {
        float s = b2[r * 32 + tid];
        for (int j = 0; j < 64; ++j)
            s = fmaf(h_s[j], w2[(r * 64 + j) * 32 + tid], s);
        float gate = 1.f / (1.f + expf(-s));
        f_s[tid] = gate * roi_s[tid];
    }
    __syncthreads();
    {
        float s = pb1[r * 64 + tid];
        for (int c = 0; c < 32; ++c)
            s = fmaf(f_s[c], pw1[(r * 32 + c) * 64 + tid], s);
        p_s[tid] = fmaxf(s, 0.f);
    }
    __syncthreads();
    if (tid < 32) {
        float s = pb2[r * 32 + tid];
        for (int j = 0; j < 64; ++j)
            s = fmaf(p_s[j], pw2[(r * 64 + j) * 32 + tid], s);
        out[((size_t)b * 90 + r) * 32 + tid] = s;
    }
}

// ---------------------------------------------------------------------------
extern "C" void kernel_launch(void* const* d_in, const int* in_sizes, int n_in,
                              void* d_out, int out_size, void* d_ws, size_t ws_size,
                              hipStream_t stream)
{
    const float* data    = (const float*)d_in[0];
    const float* mask    = (const float*)d_in[1];
    const float* conv0_w = (const float*)d_in[2];
    const float* convs_w = (const float*)d_in[4];
    const float* sw1 = (const float*)d_in[6];
    const float* sb1 = (const float*)d_in[7];
    const float* sw2 = (const float*)d_in[8];
    const float* sb2 = (const float*)d_in[9];
    const float* pw1 = (const float*)d_in[10];
    const float* pb1 = (const float*)d_in[11];
    const float* pw2 = (const float*)d_in[12];
    const float* pb2 = (const float*)d_in[13];
    float* out = (float*)d_out;

    float* ws = (float*)d_ws;
    unsigned short* bufA = (unsigned short*)ws;                  // 16,777,216 bf16
    unsigned short* bufB = (unsigned short*)(ws + 8388608);      // 16,777,216 bf16
    unsigned short* wpad = (unsigned short*)(ws + 16777216);     // 221,184 ushort
    float* zeroreg = ws + 16887808;
    float* raw     = zeroreg;            // 512
    float* cnt     = zeroreg + 6272;     // 90
    float* stats   = zeroreg + 6362;     // 512
    unsigned long long* bits = (unsigned long long*)(ws + 16894720);  // 368,640 u64
    float* part    = ws + 17825792;      // NPART*96*64 = 6,291,456 floats (25MB)

    hipMemsetAsync(zeroreg, 0, 6362 * sizeof(float), stream);
    prep_w_k<<<432, 256, 0, stream>>>(conv0_w, convs_w, wpad);

    // layer 0: data(fp32) -> bufA (bf16 channels-last)
    hipLaunchKernelGGL((conv_mfma_k<true>), dim3(1024), dim3(512), 0, stream,
                       (const void*)data, wpad, (const float*)nullptr, bufA, raw);
    stats_final_k<<<1, 64, 0, stream>>>(raw, stats);
    // layer 1: bufA -> bufB
    hipLaunchKernelGGL((conv_mfma_k<false>), dim3(1024), dim3(512), 0, stream,
                       (const void*)bufA, wpad + 55296, stats, bufB, raw + 128);
    stats_final_k<<<1, 64, 0, stream>>>(raw + 128, stats + 128);
    // layer 2: bufB -> bufA
    hipLaunchKernelGGL((conv_mfma_k<false>), dim3(1024), dim3(512), 0, stream,
                       (const void*)bufB, wpad + 2 * 55296, stats + 128, bufA, raw + 256);
    stats_final_k<<<1, 64, 0, stream>>>(raw + 256, stats + 256);
    // layer 3: bufA -> bufB (bf16 channels-last)
    hipLaunchKernelGGL((conv_mfma_k<false>), dim3(1024), dim3(512), 0, stream,
                       (const void*)bufA, wpad + 3 * 55296, stats + 256, bufB, raw + 384);
    stats_final_k<<<1, 64, 0, stream>>>(raw + 384, stats + 384);

    // mask -> bits (+counts)
    pack_mask_k<<<1440, 256, 0, stream>>>(mask, bits, cnt);

    // ROI pooling GEMM -> dense partials (no atomics)
    pool_mfma_k<<<NPART, 256, 0, stream>>>(bufB, stats + 384, bits, part);

    // per-ROI partial reduction + MLPs
    mlp_k<<<180, 64, 0, stream>>>(part, cnt, sw1, sb1, sw2, sb2,
                                  pw1, pb1, pw2, pb2, out);
}

// Round 5
// 435.630 us; speedup vs baseline: 4.6610x; 1.0533x over previous
//
#include <hip/hip_runtime.h>
#include <hip/hip_bf16.h>
#include <math.h>

#define S_TOT 262144   // 64^3
#define EPS_F 1e-5f
#define NPART 1024     // pool partial-K blocks

typedef __attribute__((ext_vector_type(8))) short s16x8;
typedef __attribute__((ext_vector_type(4))) float f32x4;

__device__ __forceinline__ unsigned short f2bf(float f) {   // RNE, manual
    unsigned u = __builtin_bit_cast(unsigned, f);
    unsigned r = (u + 0x7FFFu + ((u >> 16) & 1u)) >> 16;
    return (unsigned short)r;
}
__device__ __forceinline__ float bf2f(unsigned short u) {
    return __builtin_bit_cast(float, ((unsigned)u) << 16);
}

// ---------------------------------------------------------------------------
// Weight prep: fp32 -> bf16 hi/lo split, layout [layer][tap][hi|lo][brow][cin],
// INTERLEAVED cout mapping: brow(cout) = ((cout&1)<<4) | (cout>>1).
// Layer 0: cin=1 padded to 32 with zeros.
// ---------------------------------------------------------------------------
__global__ __launch_bounds__(256)
void prep_w_k(const float* __restrict__ conv0_w, const float* __restrict__ convs_w,
              unsigned short* __restrict__ wpad)
{
    int idx = blockIdx.x * 256 + threadIdx.x;     // 4*27*32*32 = 110592
    if (idx >= 110592) return;
    int layer = idx / 27648;
    int rem   = idx - layer * 27648;
    int tap   = rem >> 10;
    int cout  = (rem >> 5) & 31;
    int cin   = rem & 31;
    float wv;
    if (layer == 0) wv = (cin == 0) ? conv0_w[cout * 27 + tap] : 0.f;
    else            wv = convs_w[(((layer - 1) * 32 + cout) * 32 + cin) * 27 + tap];
    unsigned short hi = f2bf(wv);
    float hif = bf2f(hi);
    unsigned short lo = f2bf(wv - hif);
    int brow = ((cout & 1) << 4) | (cout >> 1);
    size_t base = ((size_t)(layer * 27 + tap) * 2) * 1024 + brow * 32 + cin;
    wpad[base]        = hi;
    wpad[base + 1024] = lo;
}

// ---------------------------------------------------------------------------
// Pipelined MFMA conv layer. 256 blocks (1/CU), 512 threads (8 waves), each
// block processes 4 consecutive 8x8x8 tiles with double-buffered LDS:
//   iter k: issue global loads for tile k+1 (regs) -> MFMA tile k (buf[p]) ->
//           stats -> convert+ds_write tile k+1 (buf[p^1]) -> direct stores ->
//           ONE barrier -> stats atomics.
// LDS tile: [10][10][10] voxels x 32ch bf16, 64B/voxel, XOR quarter-swizzle
//   q = g ^ ((vox&3) ^ ((vox>>2)&1))  on 16B quarters (bank spread).
// Output: bf16 channels-last, packed-u32 direct stores (each 16-lane cluster
// fully covers one voxel's 64B channel block -> no partial-line RMW).
// ---------------------------------------------------------------------------
template<bool FIRST>
__global__ __launch_bounds__(512, 1)
void conv_pipe_k(const void* __restrict__ in_, const unsigned short* __restrict__ wpad_l,
                 const float* __restrict__ stats_in, unsigned short* __restrict__ outb,
                 float* __restrict__ raw_out)
{
    __shared__ unsigned short buf[2][32000];   // 2 x 1000 voxels x 32ch bf16
    __shared__ float s_red[2][512];            // [pp][wave][cout][sum|sumsq]

    const int tid  = threadIdx.x;
    const int lane = tid & 63;
    const int wv   = tid >> 6;        // wave = z-plane 0..7
    const int row  = lane & 15;
    const int g4   = lane >> 4;
    const int g    = tid & 3;         // staging channel-group (fixed: 512%4==0)
    const int vox0 = tid >> 2;        // 0..127

    const int t40 = blockIdx.x << 2;  // first tile index of this block
    const int b   = t40 >> 9;         // batch (constant across the 4 tiles)

    // per-thread norm constants for staging channel group g
    float rs[8], sh[8];
    if (!FIRST) {
        #pragma unroll
        for (int j = 0; j < 8; ++j) {
            float m = stats_in[(b * 32 + g * 8 + j) * 2];
            float r = stats_in[(b * 32 + g * 8 + j) * 2 + 1];
            rs[j] = r; sh[j] = -m * r;
        }
    }

    int vbase[4];
    #pragma unroll
    for (int f = 0; f < 4; ++f) {
        int vvx = f * 16 + row;
        vbase[f] = wv * 100 + (vvx >> 3) * 10 + (vvx & 7);
    }

    s16x8 pend[8];
    float pendf[8];
    int   okm = 0;

    // ---- issue: global loads for tile k into pend regs ----
    auto issue = [&](int k) {
        int t  = (t40 + k) & 511;
        int x0 = (t & 7) << 3, y0 = ((t >> 3) & 7) << 3, z0 = (t >> 6) << 3;
        okm = 0;
        #pragma unroll
        for (int u = 0; u < 8; ++u) {
            int vox = vox0 + u * 128;
            int zz = vox / 100, r2 = vox - zz * 100, yy = r2 / 10, xx = r2 - yy * 10;
            int gz = z0 + zz - 1, gy = y0 + yy - 1, gx = x0 + xx - 1;
            bool ok = (vox < 1000) && ((unsigned)gz < 64u) && ((unsigned)gy < 64u)
                      && ((unsigned)gx < 64u);
            okm |= ((int)ok) << u;
            if (FIRST) {
                float v = 0.f;
                if (ok && g == 0)
                    v = ((const float*)in_)[((size_t)b << 18) + (gz << 12) + (gy << 6) + gx];
                pendf[u] = v;
            } else {
                s16x8 v = (s16x8)0;
                if (ok)
                    v = *(const s16x8*)((const unsigned short*)in_
                        + ((((size_t)b << 18) + (gz << 12) + (gy << 6) + gx) << 5) + (g << 3));
                pend[u] = v;
            }
        }
    };

    // ---- commit: normalize + ds_write pend into buf[pp] ----
    auto commit = [&](int pp) {
        unsigned short* bp = buf[pp];
        #pragma unroll
        for (int u = 0; u < 8; ++u) {
            int vox = vox0 + u * 128;
            if (vox >= 1000) continue;
            bool ok = (okm >> u) & 1;
            s16x8 vec = (s16x8)0;
            if (FIRST) {
                if (g == 0) vec[0] = (short)f2bf(pendf[u]);
            } else if (ok) {
                #pragma unroll
                for (int j = 0; j < 8; ++j) {
                    float v = bf2f((unsigned short)pend[u][j]);
                    vec[j] = (short)f2bf(fmaxf(0.f, fmaf(v, rs[j], sh[j])));
                }
            }
            int q = g ^ ((vox & 3) ^ ((vox >> 2) & 1));
            *(s16x8*)&bp[(vox << 5) + (q << 3)] = vec;
        }
    };

    // ================= pipeline =================
    issue(0);
    commit(0);
    __syncthreads();

    int p = 0;
    for (int k = 0; k < 4; ++k) {
        if (k < 3) issue(k + 1);

        // ---- MFMA over buf[p] ----
        const unsigned short* bp = buf[p];
        f32x4 acc[4][2] = {};
        s16x8 wh0 = *(const s16x8*)(wpad_l + row * 32 + g4 * 8);
        s16x8 wh1 = *(const s16x8*)(wpad_l + (16 + row) * 32 + g4 * 8);
        s16x8 wl0 = *(const s16x8*)(wpad_l + 1024 + row * 32 + g4 * 8);
        s16x8 wl1 = *(const s16x8*)(wpad_l + 1024 + (16 + row) * 32 + g4 * 8);

        #pragma unroll 1
        for (int tap = 0; tap < 27; ++tap) {
            int ntap = (tap < 26) ? tap + 1 : 26;
            const unsigned short* wn = wpad_l + ntap * 2048;
            s16x8 nh0 = *(const s16x8*)(wn + row * 32 + g4 * 8);
            s16x8 nh1 = *(const s16x8*)(wn + (16 + row) * 32 + g4 * 8);
            s16x8 nl0 = *(const s16x8*)(wn + 1024 + row * 32 + g4 * 8);
            s16x8 nl1 = *(const s16x8*)(wn + 1024 + (16 + row) * 32 + g4 * 8);

            int dz = tap / 9, r9 = tap - dz * 9, dy = r9 / 3, dx = r9 - dy * 3;
            int dvox = dz * 100 + dy * 10 + dx;
            #pragma unroll
            for (int f = 0; f < 4; ++f) {
                int v = vbase[f] + dvox;
                int q = g4 ^ ((v & 3) ^ ((v >> 2) & 1));
                s16x8 a = *(const s16x8*)&bp[(v << 5) + (q << 3)];
                acc[f][0] = __builtin_amdgcn_mfma_f32_16x16x32_bf16(a, wh0, acc[f][0], 0, 0, 0);
                acc[f][0] = __builtin_amdgcn_mfma_f32_16x16x32_bf16(a, wl0, acc[f][0], 0, 0, 0);
                acc[f][1] = __builtin_amdgcn_mfma_f32_16x16x32_bf16(a, wh1, acc[f][1], 0, 0, 0);
                acc[f][1] = __builtin_amdgcn_mfma_f32_16x16x32_bf16(a, wl1, acc[f][1], 0, 0, 0);
            }
            wh0 = nh0; wh1 = nh1; wl0 = nl0; wl1 = nl1;
        }

        // ---- instance-norm partial stats ----
        {
            float s0 = 0.f, ss0 = 0.f, s1 = 0.f, ss1 = 0.f;
            #pragma unroll
            for (int f = 0; f < 4; ++f) {
                #pragma unroll
                for (int q = 0; q < 4; ++q) {
                    float v0 = acc[f][0][q], v1 = acc[f][1][q];
                    s0 += v0; ss0 += v0 * v0; s1 += v1; ss1 += v1 * v1;
                }
            }
            s0 += __shfl_xor(s0, 16); s0 += __shfl_xor(s0, 32);
            ss0 += __shfl_xor(ss0, 16); ss0 += __shfl_xor(ss0, 32);
            s1 += __shfl_xor(s1, 16); s1 += __shfl_xor(s1, 32);
            ss1 += __shfl_xor(ss1, 16); ss1 += __shfl_xor(ss1, 32);
            if (lane < 16) {
                s_red[p][(wv * 32 + 2 * row) * 2]         = s0;
                s_red[p][(wv * 32 + 2 * row) * 2 + 1]     = ss0;
                s_red[p][(wv * 32 + 2 * row + 1) * 2]     = s1;
                s_red[p][(wv * 32 + 2 * row + 1) * 2 + 1] = ss1;
            }
        }

        // ---- stage next tile into the other buffer ----
        if (k < 3) commit(p ^ 1);

        // ---- direct packed stores (channels-last bf16) ----
        {
            int t  = (t40 + k) & 511;
            int x0 = (t & 7) << 3, y0 = ((t >> 3) & 7) << 3, z0 = (t >> 6) << 3;
            unsigned short* ob = outb
                + ((((size_t)b << 18) + ((size_t)(z0 + wv) << 12) + (y0 << 6) + x0) << 5)
                + (row << 1);
            #pragma unroll
            for (int f = 0; f < 4; ++f) {
                #pragma unroll
                for (int qq = 0; qq < 4; ++qq) {
                    int u = g4 * 4 + qq;
                    int yy = f * 2 + (u >> 3), xx = u & 7;
                    unsigned pk = (unsigned)f2bf(acc[f][0][qq])
                                | ((unsigned)f2bf(acc[f][1][qq]) << 16);
                    *(unsigned*)(ob + ((yy << 6) + xx) * 32) = pk;
                }
            }
        }

        __syncthreads();   // buf[p^1] staged; buf[p] free; s_red[p] complete

        if (tid < 64) {
            int n = tid & 31, sel = tid >> 5;
            float tot = 0.f;
            #pragma unroll
            for (int w = 0; w < 8; ++w) tot += s_red[p][(w * 32 + n) * 2 + sel];
            atomicAdd(&raw_out[(b * 32 + n) * 2 + sel], tot);
        }
        p ^= 1;
    }
}

__global__ void stats_final_k(const float* __restrict__ raw, float* __restrict__ stats)
{
    int bc = threadIdx.x;   // 64
    float mean = raw[bc * 2] * (1.f / 262144.f);
    float var  = raw[bc * 2 + 1] * (1.f / 262144.f) - mean * mean;
    stats[bc * 2]     = mean;
    stats[bc * 2 + 1] = rsqrtf(var + EPS_F);
}

// ---------------------------------------------------------------------------
// Pack 0/1 float mask into bits (u64 per 64 voxels) + per-ROI voxel counts.
// ---------------------------------------------------------------------------
__global__ __launch_bounds__(256)
void pack_mask_k(const float* __restrict__ mask, unsigned long long* __restrict__ bits,
                 float* __restrict__ cnt)
{
    const int r = blockIdx.x >> 4, part = blockIdx.x & 15;
    const int lane = threadIdx.x & 63, wv = threadIdx.x >> 6;
    const size_t base = (size_t)r * S_TOT + part * 16384;
    int local = 0;
    for (int wd = wv; wd < 256; wd += 4) {
        float v = mask[base + wd * 64 + lane];
        unsigned long long bm = __ballot(v != 0.f);
        if (lane == 0) { bits[r * 4096 + part * 256 + wd] = bm; local += __popcll(bm); }
    }
    if (lane == 0) atomicAdd(&cnt[r], (float)local);
}

// ---------------------------------------------------------------------------
// ROI pooling as MFMA GEMM: D[bc=64][r=96] += A[bc][s] * B[s][r]
// A = norm+relu(emb bf16 channels-last), transposed into LDS on load.
// B = mask bits -> bf16.  NPART blocks x 2 chunks x 128 s.
// Dense per-block partial tile store (no atomics) -> part[block][96][64].
// ---------------------------------------------------------------------------
__global__ __launch_bounds__(256)
void pool_mfma_k(const unsigned short* __restrict__ emb, const float* __restrict__ stats3,
                 const unsigned long long* __restrict__ bits, float* __restrict__ part)
{
    __shared__ unsigned short Ald[64 * 136];   // [bc][k=128] bf16
    __shared__ unsigned short Bld[96 * 136];   // [r][k=128] bf16
    __shared__ float s_ns[128];                // rs[64] | -m*rs[64]

    const int tid  = threadIdx.x;
    const int lane = tid & 63, wv = tid >> 6;
    const int row  = lane & 15, g4 = lane >> 4;

    if (tid < 64) {
        float m = stats3[tid * 2], rs = stats3[tid * 2 + 1];
        s_ns[tid]      = rs;
        s_ns[64 + tid] = -m * rs;
    }

    f32x4 acc[6] = {};

    for (int ch = 0; ch < 2; ++ch) {
        const int s0 = (blockIdx.x * 2 + ch) << 7;
        __syncthreads();
        // stage A: channels-last bf16 -> normalized [bc][s] (transpose on load)
        for (int i = tid; i < 1024; i += 256) {
            int bb = i >> 9, v = (i >> 2) & 127, g = i & 3;
            const unsigned short* p = emb + (((size_t)bb << 18) + (size_t)(s0 + v)) * 32 + (g << 3);
            s16x8 rv = *(const s16x8*)p;
            #pragma unroll
            for (int j = 0; j < 8; ++j) {
                int bc = bb * 32 + (g << 3) + j;
                float vf = bf2f((unsigned short)rv[j]);
                float nv = fmaxf(0.f, fmaf(vf, s_ns[bc], s_ns[64 + bc]));
                Ald[bc * 136 + v] = f2bf(nv);
            }
        }
        // stage B: bit-expand mask to bf16 (r >= 90 -> zeros)
        for (int i = tid; i < 1536; i += 256) {
            int r = i >> 4, bs = i & 15;
            s16x8 vec = (s16x8)0;
            if (r < 90) {
                unsigned long long w = bits[r * 4096 + (s0 >> 6) + (bs >> 3)];
                unsigned byte = (unsigned)(w >> ((bs & 7) * 8)) & 0xFFu;
                #pragma unroll
                for (int j = 0; j < 8; ++j)
                    vec[j] = ((byte >> j) & 1u) ? (short)0x3F80 : (short)0;
            }
            *(s16x8*)&Bld[r * 136 + bs * 8] = vec;
        }
        __syncthreads();
        #pragma unroll
        for (int kk = 0; kk < 4; ++kk) {
            s16x8 a = *(const s16x8*)&Ald[(wv * 16 + row) * 136 + kk * 32 + g4 * 8];
            #pragma unroll
            for (int j = 0; j < 6; ++j) {
                s16x8 bb = *(const s16x8*)&Bld[(j * 16 + row) * 136 + kk * 32 + g4 * 8];
                acc[j] = __builtin_amdgcn_mfma_f32_16x16x32_bf16(a, bb, acc[j], 0, 0, 0);
            }
        }
    }
    #pragma unroll
    for (int j = 0; j < 6; ++j) {
        *(f32x4*)&part[((size_t)blockIdx.x * 96 + j * 16 + row) * 64 + wv * 16 + g4 * 4]
            = acc[j];
    }
}

// ---------------------------------------------------------------------------
// Per-ROI partial reduction + gated MLP + projection. One block (64 threads)
// per (b, r).
// ---------------------------------------------------------------------------
__global__ __launch_bounds__(64)
void mlp_k(const float* __restrict__ part, const float* __restrict__ cnt,
           const float* __restrict__ w1, const float* __restrict__ b1,
           const float* __restrict__ w2, const float* __restrict__ b2,
           const float* __restrict__ pw1, const float* __restrict__ pb1,
           const float* __restrict__ pw2, const float* __restrict__ pb2,
           float* __restrict__ out)
{
    const int r   = blockIdx.x % 90;
    const int b   = blockIdx.x / 90;
    const int tid = threadIdx.x;
    __shared__ float roi_s[32], h_s[64], f_s[32], p_s[64];

    {
        const int c = tid & 31, h = tid >> 5;
        const float* pp = part + ((size_t)(h * (NPART / 2)) * 96 + r) * 64 + b * 32 + c;
        float s = 0.f;
        #pragma unroll 4
        for (int p = 0; p < NPART / 2; ++p) s += pp[(size_t)p * 6144];
        s += __shfl_down(s, 32);
        if (tid < 32) roi_s[tid] = s / cnt[r];
    }
    __syncthreads();
    {
        float s = b1[r * 64 + tid];
        for (int c = 0; c < 32; ++c)
            s = fmaf(roi_s[c], w1[(r * 32 + c) * 64 + tid], s);
        h_s[tid] = fmaxf(s, 0.f);
    }
    __syncthreads();
    if (tid < 32) {
        float s = b2[r * 32 + tid];
        for (int j = 0; j < 64; ++j)
            s = fmaf(h_s[j], w2[(r * 64 + j) * 32 + tid], s);
        float gate = 1.f / (1.f + expf(-s));
        f_s[tid] = gate * roi_s[tid];
    }
    __syncthreads();
    {
        float s = pb1[r * 64 + tid];
        for (int c = 0; c < 32; ++c)
            s = fmaf(f_s[c], pw1[(r * 32 + c) * 64 + tid], s);
        p_s[tid] = fmaxf(s, 0.f);
    }
    __syncthreads();
    if (tid < 32) {
        float s = pb2[r * 32 + tid];
        for (int j = 0; j < 64; ++j)
            s = fmaf(p_s[j], pw2[(r * 64 + j) * 32 + tid], s);
        out[((size_t)b * 90 + r) * 32 + tid] = s;
    }
}

// ---------------------------------------------------------------------------
extern "C" void kernel_launch(void* const* d_in, const int* in_sizes, int n_in,
                              void* d_out, int out_size, void* d_ws, size_t ws_size,
                              hipStream_t stream)
{
    const float* data    = (const float*)d_in[0];
    const float* mask    = (const float*)d_in[1];
    const float* conv0_w = (const float*)d_in[2];
    const float* convs_w = (const float*)d_in[4];
    const float* sw1 = (const float*)d_in[6];
    const float* sb1 = (const float*)d_in[7];
    const float* sw2 = (const float*)d_in[8];
    const float* sb2 = (const float*)d_in[9];
    const float* pw1 = (const float*)d_in[10];
    const float* pb1 = (const float*)d_in[11];
    const float* pw2 = (const float*)d_in[12];
    const float* pb2 = (const float*)d_in[13];
    float* out = (float*)d_out;

    float* ws = (float*)d_ws;
    unsigned short* bufA = (unsigned short*)ws;                  // 16,777,216 bf16
    unsigned short* bufB = (unsigned short*)(ws + 8388608);      // 16,777,216 bf16
    unsigned short* wpad = (unsigned short*)(ws + 16777216);     // 221,184 ushort
    float* zeroreg = ws + 16887808;
    float* raw     = zeroreg;            // 512
    float* cnt     = zeroreg + 6272;     // 90
    float* stats   = zeroreg + 6362;     // 512
    unsigned long long* bits = (unsigned long long*)(ws + 16894720);  // 368,640 u64
    float* part    = ws + 17825792;      // NPART*96*64 = 6,291,456 floats (25MB)

    hipMemsetAsync(zeroreg, 0, 6362 * sizeof(float), stream);
    prep_w_k<<<432, 256, 0, stream>>>(conv0_w, convs_w, wpad);

    // layer 0: data(fp32) -> bufA (bf16 channels-last)
    hipLaunchKernelGGL((conv_pipe_k<true>), dim3(256), dim3(512), 0, stream,
                       (const void*)data, wpad, (const float*)nullptr, bufA, raw);
    stats_final_k<<<1, 64, 0, stream>>>(raw, stats);
    // layer 1: bufA -> bufB
    hipLaunchKernelGGL((conv_pipe_k<false>), dim3(256), dim3(512), 0, stream,
                       (const void*)bufA, wpad + 55296, stats, bufB, raw + 128);
    stats_final_k<<<1, 64, 0, stream>>>(raw + 128, stats + 128);
    // layer 2: bufB -> bufA
    hipLaunchKernelGGL((conv_pipe_k<false>), dim3(256), dim3(512), 0, stream,
                       (const void*)bufB, wpad + 2 * 55296, stats + 128, bufA, raw + 256);
    stats_final_k<<<1, 64, 0, stream>>>(raw + 256, stats + 256);
    // layer 3: bufA -> bufB (bf16 channels-last)
    hipLaunchKernelGGL((conv_pipe_k<false>), dim3(256), dim3(512), 0, stream,
                       (const void*)bufA, wpad + 3 * 55296, stats + 256, bufB, raw + 384);
    stats_final_k<<<1, 64, 0, stream>>>(raw + 384, stats + 384);

    // mask -> bits (+counts)
    pack_mask_k<<<1440, 256, 0, stream>>>(mask, bits, cnt);

    // ROI pooling GEMM -> dense partials (no atomics)
    pool_mfma_k<<<NPART, 256, 0, stream>>>(bufB, stats + 384, bits, part);

    // per-ROI partial reduction + MLPs
    mlp_k<<<180, 64, 0, stream>>>(part, cnt, sw1, sb1, sw2, sb2,
                                  pw1, pb1, pw2, pb2, out);
}